// Round 8
// baseline (283.138 us; speedup 1.0000x reference)
//
#include <hip/hip_runtime.h>
#include <hip/hip_bf16.h>

// Problem constants (from reference)
#define BATCH 2
#define SEQ   2048
#define DMODEL 1024
#define NHEAD 16
#define DK    64
#define MTOK  (BATCH * SEQ)      // 4096 token rows

typedef __attribute__((ext_vector_type(8))) short bf16x8;   // 8 bf16 in 4 VGPRs
typedef __attribute__((ext_vector_type(4))) float f32x4;    // MFMA 16x16 accumulator

// float -> bf16 bits, round-to-nearest-even
__device__ __forceinline__ unsigned short f2bf(float x) {
    unsigned u = __float_as_uint(x);
    u = (u + 0x7FFFu + ((u >> 16) & 1u)) >> 16;
    return (unsigned short)u;
}

__device__ __forceinline__ void store_out(float* p, float v)          { *p = v; }
__device__ __forceinline__ void store_out(unsigned short* p, float v) { *p = f2bf(v); }

// packed f32x2 -> bf16x2 (RNE, same rounding as f2bf), lo = x, hi = y
__device__ __forceinline__ unsigned cvt_pk_bf16(float x, float y) {
    unsigned d;
    asm("v_cvt_pk_bf16_f32 %0, %1, %2" : "=v"(d) : "v"(x), "v"(y));
    return d;
}

// async global->LDS, 16 B per lane; LDS dest = wave-uniform base + lane*16.
__device__ __forceinline__ void g2lds16(const void* g, void* l) {
    __builtin_amdgcn_global_load_lds(
        (const __attribute__((address_space(1))) void*)g,
        (__attribute__((address_space(3))) void*)l, 16, 0, 0);
}

template <int N>
__device__ __forceinline__ void s_wait_vmcnt() {
    asm volatile("s_waitcnt vmcnt(%0)" :: "n"(N) : "memory");
}
__device__ __forceinline__ void s_wait_lgkm0() {
    asm volatile("s_waitcnt lgkmcnt(0)" ::: "memory");
}
__device__ __forceinline__ void s_bar() {
    asm volatile("s_barrier" ::: "memory");
}

// ---------------------------------------------------------------------------
// Transpose + convert the 4 weight matrices: Wt[n][k] = (bf16)W[k][n], 1024^2.
// ---------------------------------------------------------------------------
__global__ __launch_bounds__(256) void wtrans_kernel(
    const float* __restrict__ w0, const float* __restrict__ w1,
    const float* __restrict__ w2, const float* __restrict__ w3,
    unsigned short* __restrict__ t0, unsigned short* __restrict__ t1,
    unsigned short* __restrict__ t2, unsigned short* __restrict__ t3)
{
    __shared__ float tile[32][33];
    const float* W; unsigned short* T;
    switch (blockIdx.z) {
        case 0:  W = w0; T = t0; break;
        case 1:  W = w1; T = t1; break;
        case 2:  W = w2; T = t2; break;
        default: W = w3; T = t3; break;
    }
    const int n0 = blockIdx.x * 32, k0 = blockIdx.y * 32;
    const int t  = threadIdx.x;
    const int r  = t >> 3;          // 0..31
    const int c4 = (t & 7) * 4;     // 0..28

    float4 v = *(const float4*)&W[(size_t)(k0 + r) * DMODEL + n0 + c4];
    tile[r][c4 + 0] = v.x; tile[r][c4 + 1] = v.y;
    tile[r][c4 + 2] = v.z; tile[r][c4 + 3] = v.w;
    __syncthreads();

    union { unsigned short s[4]; uint2 u; } o;
#pragma unroll
    for (int u = 0; u < 4; ++u) o.s[u] = f2bf(tile[c4 + u][r]);
    *(uint2*)&T[(size_t)(n0 + r) * DMODEL + k0 + c4] = o.u;
}

// ---------------------------------------------------------------------------
// MFMA GEMM, round-14: fp32 operand CONVERSION FUSED into staging.
// Rationale: four schedule variants (r4-r7) all land 61-65 us — the QKV GEMM
// is at its practical floor for this size/parallelism regime (above the m102
// reference curve). The remaining lever is whole-kernel/traffic elimination:
// cvt3 (fp32->bf16 of q,k,v; ~48 MB read + 24 MB write + a launch) is deleted
// by reg-staging the fp32 side here: float4 x2 -> v_cvt_pk_bf16_f32 (RNE,
// bit-identical to f2bf) -> ds_write_b128 into the same fragment-ordered slot
// g2lds would fill. The bf16 (weight) side keeps global_load_lds.
// Sync skeleton = r4 two-barrier form (measured fastest):
//   [compute cur] -> lgkm0 -> B1(bar, cur retired) ->
//   [issue fp32(kt+2), sched_barrier, issue g2lds(kt+2) into cur;
//    vmcnt(4) = {kt+1 g2lds + kt+2 fp32} drained; cvt+ds_write] -> B2(bar).
// Slot assignment transposed (s = i*8 + w) so each wave owns 4 A-slots +
// 4 B-slots; exactly one side is fp32 per z (z0/z1: A=q/k; z2: B=v), so
// per-wave counts are uniform: 8 fp32 items + 4 g2lds items per tile.
// ds_write completion for tile kt+1 is covered by B1's lgkm0 of step kt.
// ---------------------------------------------------------------------------
struct GemmP {
    const unsigned short* A;    // bf16 A side (if !aF32)
    const unsigned short* Bt;   // bf16 B side (if !bF32)
    const float* A32;           // fp32 A side (if aF32)
    const float* B32;           // fp32 B side (if bF32)
    const float* bias;
    void* C;
    int N, K, ctShift, biasByRow, aF32, bF32;
    float scale;
};
struct Gemm3 { GemmP p[3]; };

template <typename OutT, int MR, int NC, bool HASF32>
__device__ __forceinline__ void gemm_body(const Gemm3& g)
{
    constexpr int AM    = MR / 2;            // per-wave row fragments
    constexpr int NCW   = NC / 4;            // per-wave column fragments
    constexpr int NBLK  = 2 * MR + 2 * NC;   // 512-short staging blocks/buffer
    constexpr int PW    = NBLK / 8;          // slots per wave per K-step
    constexpr int NF    = HASF32 ? PW / 2 : 0;   // fp32 slots per wave
    constexpr int NG    = PW - NF;               // bf16 g2lds slots per wave
    constexpr int BUFSZ = NBLK * 512;        // shorts per buffer

    __shared__ unsigned short sS[2 * BUFSZ];

    // XCD-aware remap across the whole linear grid (launcher guarantees %8==0)
    const unsigned nx  = gridDim.x;
    const unsigned lin = blockIdx.x + nx * blockIdx.z;
    const unsigned ch  = (nx * gridDim.z) >> 3;
    const unsigned l2  = (lin & 7u) * ch + (lin >> 3);
    const unsigned zz  = l2 / nx;
    const unsigned bid = l2 - zz * nx;

    const GemmP p = g.p[zz];
    OutT* __restrict__ C = (OutT*)p.C;
    const int K = p.K, N = p.N;

    const int bx = (int)(bid & ((1u << p.ctShift) - 1u));
    const int by = (int)(bid >> p.ctShift);
    const int row0 = by * (MR * 16);
    const int col0 = bx * (NC * 16);

    const int t    = threadIdx.x;
    const int w    = t >> 6;        // 0..7
    const int lane = t & 63;
    const int ln   = lane & 15;
    const int qg   = lane >> 4;
    const int wm   = w >> 2;        // 0..1  (row halves)
    const int wn   = w & 3;         // 0..3  (col quarters)

    // slot s -> row index + k base (A side: s<2*MR rows; B side: cols)
    // transposed assignment: wave w owns slots s = i*8 + w, i = 0..PW-1.
    // i < PW/2 (== 2*MR/8) -> A side, else B side (MR == NC in all uses).
    const bool aF = HASF32 && (p.aF32 != 0);

    const unsigned short* spG[NG];
    int loG[NG];
#pragma unroll
    for (int j = 0; j < NG; ++j) {
        const int i = HASF32 ? (aF ? NF + j : j) : j;
        const int s = i * 8 + w;
        if (s < 2 * MR) {
            const int mtg = s >> 1, kc = s & 1;
            spG[j] = p.A + (size_t)(row0 + mtg * 16 + ln) * K + kc * 32 + qg * 8;
        } else {
            const int bi = s - 2 * MR, ntg = bi >> 1, kc = bi & 1;
            spG[j] = p.Bt + (size_t)(col0 + ntg * 16 + ln) * K + kc * 32 + qg * 8;
        }
        loG[j] = s * 512;
    }

    const float* spF[NF > 0 ? NF : 1];
    int loF[NF > 0 ? NF : 1];
    if constexpr (HASF32) {
#pragma unroll
        for (int j = 0; j < NF; ++j) {
            const int i = aF ? j : NF + j;
            const int s = i * 8 + w;
            if (s < 2 * MR) {
                const int mtg = s >> 1, kc = s & 1;
                spF[j] = p.A32 + (size_t)(row0 + mtg * 16 + ln) * K + kc * 32 + qg * 8;
            } else {
                const int bi = s - 2 * MR, ntg = bi >> 1, kc = bi & 1;
                spF[j] = p.B32 + (size_t)(col0 + ntg * 16 + ln) * K + kc * 32 + qg * 8;
            }
            loF[j] = s * 512;
        }
    }

    float4 rA[NF > 0 ? NF : 1], rB[NF > 0 ? NF : 1];

    f32x4 acc[AM][NCW];
#pragma unroll
    for (int mt = 0; mt < AM; ++mt)
#pragma unroll
        for (int nt = 0; nt < NCW; ++nt) acc[mt][nt] = (f32x4){0.f, 0.f, 0.f, 0.f};

    const int NT = K / 64;

    // ---- staging helpers (unrolled, compile-time j) ----
    auto issueF = [&](int koff) {
        if constexpr (HASF32) {
#pragma unroll
            for (int j = 0; j < NF; ++j) {
                rA[j] = *(const float4*)(spF[j] + koff);
                rB[j] = *(const float4*)(spF[j] + koff + 4);
            }
        }
    };
    auto issueG = [&](int koff, int dstOff) {
#pragma unroll
        for (int j = 0; j < NG; ++j)
            g2lds16(spG[j] + koff, &sS[dstOff + loG[j]]);
    };
    auto cvtWrite = [&](int dstOff) {
        if constexpr (HASF32) {
#pragma unroll
            for (int j = 0; j < NF; ++j) {
                uint4 o;
                o.x = cvt_pk_bf16(rA[j].x, rA[j].y);
                o.y = cvt_pk_bf16(rA[j].z, rA[j].w);
                o.z = cvt_pk_bf16(rB[j].x, rB[j].y);
                o.w = cvt_pk_bf16(rB[j].z, rB[j].w);
                *(uint4*)&sS[dstOff + loF[j] + lane * 8] = o;
            }
        }
    };

    // ---- prologue: tile 0 -> buf0 (full), tile 1 -> buf1 ----
    issueF(0);
    __builtin_amdgcn_sched_barrier(0);
    issueG(0, 0);
    cvtWrite(0);                         // compiler waits the rA/rB deps
    issueF(64);
    __builtin_amdgcn_sched_barrier(0);
    issueG(64, BUFSZ);
    cvtWrite(BUFSZ);
    s_wait_vmcnt<4>();                   // tile0 g2lds drained (tile1's may remain)
    s_wait_lgkm0();                      // all ds_writes done
    s_bar();

    for (int kt = 0; kt < NT; ++kt) {
        const int boff = (kt & 1) ? BUFSZ : 0;
        const unsigned short* bufA = &sS[boff];
        const unsigned short* bufB = &sS[boff + 2 * MR * 512];

        // ---- compute tile kt ----
#pragma unroll
        for (int kc = 0; kc < 2; ++kc) {
            bf16x8 aFr[AM], bFr[NCW];
#pragma unroll
            for (int mt = 0; mt < AM; ++mt)
                aFr[mt] = *(const bf16x8*)&bufA[((wm * AM + mt) * 2 + kc) * 512 + lane * 8];
#pragma unroll
            for (int n2 = 0; n2 < NCW; ++n2)
                bFr[n2] = *(const bf16x8*)&bufB[((wn * NCW + n2) * 2 + kc) * 512 + lane * 8];
            __builtin_amdgcn_s_setprio(1);
#pragma unroll
            for (int mt = 0; mt < AM; ++mt)
#pragma unroll
                for (int n2 = 0; n2 < NCW; ++n2)
                    acc[mt][n2] = __builtin_amdgcn_mfma_f32_16x16x32_bf16(
                        aFr[mt], bFr[n2], acc[mt][n2], 0, 0, 0);
            __builtin_amdgcn_s_setprio(0);
        }

        // B1: all my ds ops done (frag reads of cur; ds_writes of tile kt+1
        // issued last step) -> barrier retires cur block-wide and publishes
        // the kt+1 ds_writes.
        s_wait_lgkm0();
        s_bar();

        if (kt + 2 < NT) {
            const int koff = (kt + 2) * 64;
            issueF(koff);
            __builtin_amdgcn_sched_barrier(0);
            issueG(koff, boff);              // into just-retired buffer
            __builtin_amdgcn_sched_barrier(0);
            // queue (oldest first): [kt+1 g2lds(4)] [kt+2 fp32(8)] [kt+2 g2lds(4)]
            // vmcnt(4): kt+1's g2lds AND kt+2's fp32 regs drained; kt+2 g2lds fly on.
            s_wait_vmcnt<4>();
            cvtWrite(boff);
        } else {
            s_wait_vmcnt<0>();               // drain last tile's g2lds
        }
        s_bar();                             // B2: tile kt+1 published
    }

    float bcol[NCW], brow[AM][4];
    if (!p.biasByRow) {
#pragma unroll
        for (int n2 = 0; n2 < NCW; ++n2)
            bcol[n2] = p.bias[col0 + (wn * NCW + n2) * 16 + ln];
    } else {
#pragma unroll
        for (int mt = 0; mt < AM; ++mt)
#pragma unroll
            for (int r = 0; r < 4; ++r)
                brow[mt][r] = p.bias[row0 + wm * (AM * 16) + mt * 16 + qg * 4 + r];
    }

#pragma unroll
    for (int mt = 0; mt < AM; ++mt)
#pragma unroll
        for (int n2 = 0; n2 < NCW; ++n2)
#pragma unroll
            for (int r = 0; r < 4; ++r) {
                int row = row0 + wm * (AM * 16) + mt * 16 + qg * 4 + r;
                int col = col0 + (wn * NCW + n2) * 16 + ln;
                float bb = p.biasByRow ? brow[mt][r] : bcol[n2];
                store_out(&C[(size_t)row * N + col], (acc[mt][n2][r] + bb) * p.scale);
            }
}

// separately-named shells so rocprof shows QKV and out-proj independently
__global__ __launch_bounds__(512, 2) void gemm_qkv_kernel(Gemm3 g)
{
    gemm_body<unsigned short, 16, 16, true>(g);
}
__global__ __launch_bounds__(512, 2) void gemm_out_kernel(Gemm3 g)
{
    gemm_body<float, 8, 8, false>(g);
}

// ---------------------------------------------------------------------------
// Flash attention (round-10 structure, unchanged): swapped QK^T, lane-local
// softmax, in-register P exchange; no sP, LDS 40 KB.
// ---------------------------------------------------------------------------
#define BR 64
#define BC 64

__global__ __launch_bounds__(256) void attn_mfma_kernel(
    const unsigned short* __restrict__ Qg, const unsigned short* __restrict__ Kg,
    const unsigned short* __restrict__ VT, unsigned short* __restrict__ O)
{
    __shared__ unsigned short sK[2][8 * 512];   // 16 KB
    __shared__ unsigned short sV[2][8 * 512];   // 16 KB
    __shared__ unsigned short sQ[8 * 512];      // 8 KB

    const int t    = threadIdx.x;
    const int w    = t >> 6;
    const int lane = t & 63;
    const int ln   = lane & 15;
    const int qg   = lane >> 4;

    const int id  = blockIdx.x;
    const int bh  = id & 31;
    const int qt  = (SEQ / BR - 1) - (id >> 5);   // heavy tiles first
    const int b   = bh >> 4;
    const int h   = bh & 15;
    const int qi0 = qt * BR;

    const size_t rowbase = (size_t)b * SEQ;
    const size_t colbase = (size_t)h * DK;

    // ---- stage Q + K/V tile 0 (buf 0) ----
#pragma unroll
    for (int i = 0; i < 2; ++i) {
        const int s = w * 2 + i;
        const int nt = s >> 1, kc = s & 1;
        g2lds16(Qg + (rowbase + qi0 + w * 16 + ln) * DMODEL + colbase + i * 32 + qg * 8,
                &sQ[s * 512]);
        g2lds16(Kg + (rowbase + nt * 16 + ln) * DMODEL + colbase + kc * 32 + qg * 8,
                &sK[0][s * 512]);
        g2lds16(VT + (size_t)(colbase + nt * 16 + ln) * MTOK + rowbase + kc * 32 + qg * 8,
                &sV[0][s * 512]);
    }
    __syncthreads();

    // Q as B-fragment: lane holds Q[q=w*16+ln][d=kc*32+qg*8+j]
    bf16x8 aq[2];
#pragma unroll
    for (int kc = 0; kc < 2; ++kc)
        aq[kc] = *(const bf16x8*)&sQ[(w * 2 + kc) * 512 + lane * 8];

    f32x4 ofrag[4];
#pragma unroll
    for (int nt = 0; nt < 4; ++nt) ofrag[nt] = (f32x4){0.f, 0.f, 0.f, 0.f};
    float osum_p = 0.f;          // per-lane partial denom (own k-slice of q=ln)
    float m_run  = -3.0e38f;     // per-lane running max for q=ln

    // bpermute source lanes for the P-fragment exchange
    const int laneA = ((2 * qg) & 3) * 16 + ln;
    const int laneB = ((2 * qg + 1) & 3) * 16 + ln;
    const bool hiSel = (qg >> 1) & 1;

    const int ntiles = qt + 1;
    for (int jt = 0; jt < ntiles; ++jt) {
        const int cur = jt & 1;

        // ---- prefetch tile jt+1 into the alternate buffer ----
        if (jt + 1 < ntiles) {
            const int j1 = (jt + 1) * BC;
            const int nb = cur ^ 1;
#pragma unroll
            for (int i = 0; i < 2; ++i) {
                const int s = w * 2 + i;
                const int nt = s >> 1, kc = s & 1;
                g2lds16(Kg + (rowbase + j1 + nt * 16 + ln) * DMODEL + colbase + kc * 32 + qg * 8,
                        &sK[nb][s * 512]);
                g2lds16(VT + (size_t)(colbase + nt * 16 + ln) * MTOK + rowbase + j1 + kc * 32 + qg * 8,
                        &sV[nb][s * 512]);
            }
        }

        // ---- S^T = K Q^T (scores pre-scaled by 0.125*log2e) ----
        // sf[nt][r] = S[q=ln][k=nt*16+qg*4+r]
        f32x4 sf[4];
#pragma unroll
        for (int nt = 0; nt < 4; ++nt) {
            f32x4 a2 = (f32x4){0.f, 0.f, 0.f, 0.f};
#pragma unroll
            for (int kc = 0; kc < 2; ++kc) {
                bf16x8 bk = *(const bf16x8*)&sK[cur][(nt * 2 + kc) * 512 + lane * 8];
                a2 = __builtin_amdgcn_mfma_f32_16x16x32_bf16(bk, aq[kc], a2, 0, 0, 0);
            }
            sf[nt] = a2;
        }

        // ---- causal mask (diagonal tile only): k_local > q_local ----
        if (jt == ntiles - 1) {
            const int qloc = w * 16 + ln;
#pragma unroll
            for (int nt = 0; nt < 4; ++nt)
#pragma unroll
                for (int r = 0; r < 4; ++r)
                    if (nt * 16 + qg * 4 + r > qloc) sf[nt][r] = -1.0e30f;
        }

        // ---- online softmax, q-local: scalar m/alpha per lane ----
        float pmax = sf[0][0];
#pragma unroll
        for (int nt = 0; nt < 4; ++nt)
#pragma unroll
            for (int r = 0; r < 4; ++r) pmax = fmaxf(pmax, sf[nt][r]);
        pmax = fmaxf(pmax, __shfl_xor(pmax, 16));
        pmax = fmaxf(pmax, __shfl_xor(pmax, 32));

        const float mn = fmaxf(m_run, pmax);
        const float al = exp2f(m_run - mn);
        m_run = mn;

        float pv[4][4];
        float lsum = 0.f;
#pragma unroll
        for (int nt = 0; nt < 4; ++nt)
#pragma unroll
            for (int r = 0; r < 4; ++r) {
                float e = exp2f(sf[nt][r] - mn);
                pv[nt][r] = e;
                lsum += e;
            }
        osum_p = osum_p * al + lsum;

        // rescale O accumulator rows (row q = qg*4+r needs alpha from lane q)
        float alr[4];
#pragma unroll
        for (int r = 0; r < 4; ++r) alr[r] = __shfl(al, qg * 4 + r);
#pragma unroll
        for (int nt = 0; nt < 4; ++nt)
#pragma unroll
            for (int r = 0; r < 4; ++r) ofrag[nt][r] *= alr[r];

        // ---- pack P to bf16 pairs, exchange into PV A-fragments ----
        unsigned pk0[2], pk1[2], pk2[2], pk3[2];
#pragma unroll
        for (int rr = 0; rr < 2; ++rr) {
            pk0[rr] = cvt_pk_bf16(pv[0][2 * rr], pv[0][2 * rr + 1]);
            pk1[rr] = cvt_pk_bf16(pv[1][2 * rr], pv[1][2 * rr + 1]);
            pk2[rr] = cvt_pk_bf16(pv[2][2 * rr], pv[2][2 * rr + 1]);
            pk3[rr] = cvt_pk_bf16(pv[3][2 * rr], pv[3][2 * rr + 1]);
        }
        union { bf16x8 v; unsigned u[4]; } ap[2];
        {
            unsigned s0, s1;
            s0 = (unsigned)__shfl((int)pk0[0], laneA); s1 = (unsigned)__shfl((int)pk1[0], laneA);
            ap[0].u[0] = hiSel ? s1 : s0;
            s0 = (unsigned)__shfl((int)pk0[1], laneA); s1 = (unsigned)__shfl((int)pk1[1], laneA);
            ap[0].u[1] = hiSel ? s1 : s0;
            s0 = (unsigned)__shfl((int)pk0[0], laneB); s1 = (unsigned)__shfl((int)pk1[0], laneB);
            ap[0].u[2] = hiSel ? s1 : s0;
            s0 = (unsigned)__shfl((int)pk0[1], laneB); s1 = (unsigned)__shfl((int)pk1[1], laneB);
            ap[0].u[3] = hiSel ? s1 : s0;
            s0 = (unsigned)__shfl((int)pk2[0], laneA); s1 = (unsigned)__shfl((int)pk3[0], laneA);
            ap[1].u[0] = hiSel ? s1 : s0;
            s0 = (unsigned)__shfl((int)pk2[1], laneA); s1 = (unsigned)__shfl((int)pk3[1], laneA);
            ap[1].u[1] = hiSel ? s1 : s0;
            s0 = (unsigned)__shfl((int)pk2[0], laneB); s1 = (unsigned)__shfl((int)pk3[0], laneB);
            ap[1].u[2] = hiSel ? s1 : s0;
            s0 = (unsigned)__shfl((int)pk2[1], laneB); s1 = (unsigned)__shfl((int)pk3[1], laneB);
            ap[1].u[3] = hiSel ? s1 : s0;
        }

        // ---- O += P V ----
#pragma unroll
        for (int nt = 0; nt < 4; ++nt) {
#pragma unroll
            for (int kc = 0; kc < 2; ++kc) {
                bf16x8 bv = *(const bf16x8*)&sV[cur][(nt * 2 + kc) * 512 + lane * 8];
                ofrag[nt] = __builtin_amdgcn_mfma_f32_16x16x32_bf16(ap[kc].v, bv, ofrag[nt], 0, 0, 0);
            }
        }

        __syncthreads();    // publish prefetched tile; protect cur for overwrite
    }

    // ---- epilogue: finish denom across k-slices, normalize, write bf16 ----
    float osum = osum_p + __shfl_xor(osum_p, 16);
    osum += __shfl_xor(osum, 32);
    const float invq = 1.0f / osum;     // lane's q = ln
    float inv[4];
#pragma unroll
    for (int r = 0; r < 4; ++r) inv[r] = __shfl(invq, qg * 4 + r);
#pragma unroll
    for (int nt = 0; nt < 4; ++nt)
#pragma unroll
        for (int r = 0; r < 4; ++r) {
            int gq = qi0 + w * 16 + qg * 4 + r;
            O[(rowbase + gq) * DMODEL + colbase + nt * 16 + ln] =
                f2bf(ofrag[nt][r] * inv[r]);
        }
}

// ---------------------------------------------------------------------------
extern "C" void kernel_launch(void* const* d_in, const int* in_sizes, int n_in,
                              void* d_out, int out_size, void* d_ws, size_t ws_size,
                              hipStream_t stream)
{
    const float* q  = (const float*)d_in[0];
    const float* k  = (const float*)d_in[1];
    const float* v  = (const float*)d_in[2];
    // d_in[3] = mask (int32 tril) — causality applied analytically (j<=i).
    const float* wq = (const float*)d_in[4];
    const float* bq = (const float*)d_in[5];
    const float* wk = (const float*)d_in[6];
    const float* bk = (const float*)d_in[7];
    const float* wv = (const float*)d_in[8];
    const float* bv = (const float*)d_in[9];
    const float* wo = (const float*)d_in[10];
    const float* bo = (const float*)d_in[11];
    float* out = (float*)d_out;

    const size_t mat  = (size_t)MTOK * DMODEL;     // 4M elements
    const size_t wmat = (size_t)DMODEL * DMODEL;   // 1M elements
    unsigned short* WtQ = (unsigned short*)d_ws;   // bf16 transposed weights
    unsigned short* WtK = WtQ + wmat;
    unsigned short* WtV = WtK + wmat;
    unsigned short* WtO = WtV + wmat;
    unsigned short* Qb  = WtO + wmat;              // bf16 Q proj (pre-scaled)
    unsigned short* Kb  = Qb + mat;                // bf16 K proj
    unsigned short* VT  = Kb + mat;                // bf16 V proj, TRANSPOSED [D][MTOK]
    unsigned short* CTX = VT + mat;                // bf16 attention output

    wtrans_kernel<<<dim3(32, 32, 4), 256, 0, stream>>>(wq, wk, wv, wo, WtQ, WtK, WtV, WtO);

    // fused projections with IN-KERNEL fp32->bf16 of the activations:
    // z0=Q (A=q fp32, pre-scaled by 0.125*log2e), z1=K (A=k fp32),
    // z2=V transposed (swapped operands: A=WtV bf16, B=v fp32, C=VT).
    // 256x256 tiles: z0/z1: 16x4 = 64 blocks (ctShift=2); z2: 4x16 = 64
    // (ctShift=4). Total 192 (%8==0).
    const float qscale = 0.125f * 1.44269504088896f;
    Gemm3 g;
    g.p[0] = (GemmP){nullptr, WtQ, q, nullptr, bq, (void*)Qb,
                     DMODEL, DMODEL, 2, 0, 1, 0, qscale};
    g.p[1] = (GemmP){nullptr, WtK, k, nullptr, bk, (void*)Kb,
                     DMODEL, DMODEL, 2, 0, 1, 0, 1.0f};
    g.p[2] = (GemmP){WtV, nullptr, nullptr, v, bv, (void*)VT,
                     MTOK, DMODEL, 4, 1, 0, 1, 1.0f};
    gemm_qkv_kernel<<<dim3(64, 1, 3), 512, 0, stream>>>(g);

    attn_mfma_kernel<<<BATCH * NHEAD * (SEQ / BR), 256, 0, stream>>>(Qb, Kb, VT, CTX);

    // output projection: 128x128 tiles -> 32x8 = 256 blocks (all-bf16 path)
    Gemm3 go;
    go.p[0] = (GemmP){CTX, WtO, nullptr, nullptr, bo, (void*)out,
                      DMODEL, DMODEL, 3, 0, 0, 0, 1.0f};
    go.p[1] = go.p[0];
    go.p[2] = go.p[0];
    gemm_out_kernel<<<dim3(256, 1, 1), 512, 0, stream>>>(go);
}

// Round 9
// 279.706 us; speedup vs baseline: 1.0123x; 1.0123x over previous
//
#include <hip/hip_runtime.h>
#include <hip/hip_bf16.h>

// Problem constants (from reference)
#define BATCH 2
#define SEQ   2048
#define DMODEL 1024
#define NHEAD 16
#define DK    64
#define MTOK  (BATCH * SEQ)      // 4096 token rows

typedef __attribute__((ext_vector_type(8))) short bf16x8;   // 8 bf16 in 4 VGPRs
typedef __attribute__((ext_vector_type(4))) float f32x4;    // MFMA 16x16 accumulator

// float -> bf16 bits, round-to-nearest-even
__device__ __forceinline__ unsigned short f2bf(float x) {
    unsigned u = __float_as_uint(x);
    u = (u + 0x7FFFu + ((u >> 16) & 1u)) >> 16;
    return (unsigned short)u;
}

__device__ __forceinline__ void store_out(float* p, float v)          { *p = v; }
__device__ __forceinline__ void store_out(unsigned short* p, float v) { *p = f2bf(v); }

// packed f32x2 -> bf16x2 (RNE, same rounding as f2bf), lo = x, hi = y
__device__ __forceinline__ unsigned cvt_pk_bf16(float x, float y) {
    unsigned d;
    asm("v_cvt_pk_bf16_f32 %0, %1, %2" : "=v"(d) : "v"(x), "v"(y));
    return d;
}

// async global->LDS, 16 B per lane; LDS dest = wave-uniform base + lane*16.
__device__ __forceinline__ void g2lds16(const void* g, void* l) {
    __builtin_amdgcn_global_load_lds(
        (const __attribute__((address_space(1))) void*)g,
        (__attribute__((address_space(3))) void*)l, 16, 0, 0);
}

template <int N>
__device__ __forceinline__ void s_wait_vmcnt() {
    asm volatile("s_waitcnt vmcnt(%0)" :: "n"(N) : "memory");
}
__device__ __forceinline__ void s_wait_lgkm0() {
    asm volatile("s_waitcnt lgkmcnt(0)" ::: "memory");
}
__device__ __forceinline__ void s_bar() {
    asm volatile("s_barrier" ::: "memory");
}

// ---------------------------------------------------------------------------
// Merged preprocessing, one launch (saves a gap):
//   z 0..2 : fp32 -> bf16 convert of q/k/v (2048 x-blocks, 8 elems/thread)
//   z 3..4 : transpose+convert 2 weight matrices each (x encodes wgt+tile)
// ---------------------------------------------------------------------------
__global__ __launch_bounds__(256) void cvtw_kernel(
    const float* __restrict__ q, const float* __restrict__ k,
    const float* __restrict__ v,
    unsigned short* __restrict__ dq, unsigned short* __restrict__ dk,
    unsigned short* __restrict__ dv,
    const float* __restrict__ w0, const float* __restrict__ w1,
    const float* __restrict__ w2, const float* __restrict__ w3,
    unsigned short* __restrict__ t0, unsigned short* __restrict__ t1,
    unsigned short* __restrict__ t2, unsigned short* __restrict__ t3, int n)
{
    __shared__ float tile[32][33];
    if (blockIdx.z < 3) {
        const float* src; unsigned short* dst;
        switch (blockIdx.z) {
            case 0:  src = q; dst = dq; break;
            case 1:  src = k; dst = dk; break;
            default: src = v; dst = dv; break;
        }
        int i = (blockIdx.x * 256 + threadIdx.x) * 8;
        if (i >= n) return;
        float4 a = *(const float4*)(src + i);
        float4 b = *(const float4*)(src + i + 4);
        union { unsigned short s[8]; uint4 u; } o;
        o.s[0] = f2bf(a.x); o.s[1] = f2bf(a.y); o.s[2] = f2bf(a.z); o.s[3] = f2bf(a.w);
        o.s[4] = f2bf(b.x); o.s[5] = f2bf(b.y); o.s[6] = f2bf(b.z); o.s[7] = f2bf(b.w);
        *(uint4*)(dst + i) = o.u;
    } else {
        const int wi = (blockIdx.z - 3) * 2 + (blockIdx.x >> 10);
        const float* W; unsigned short* T;
        switch (wi) {
            case 0:  W = w0; T = t0; break;
            case 1:  W = w1; T = t1; break;
            case 2:  W = w2; T = t2; break;
            default: W = w3; T = t3; break;
        }
        const int ti = blockIdx.x & 1023;
        const int n0 = (ti & 31) * 32, k0 = (ti >> 5) * 32;
        const int t  = threadIdx.x;
        const int r  = t >> 3;          // 0..31
        const int c4 = (t & 7) * 4;     // 0..28

        float4 vv = *(const float4*)&W[(size_t)(k0 + r) * DMODEL + n0 + c4];
        tile[r][c4 + 0] = vv.x; tile[r][c4 + 1] = vv.y;
        tile[r][c4 + 2] = vv.z; tile[r][c4 + 3] = vv.w;
        __syncthreads();

        union { unsigned short s[4]; uint2 u; } o;
#pragma unroll
        for (int u = 0; u < 4; ++u) o.s[u] = f2bf(tile[c4 + u][r]);
        *(uint2*)&T[(size_t)(n0 + r) * DMODEL + k0 + c4] = o.u;
    }
}

// ---------------------------------------------------------------------------
// MFMA GEMM, round-15 = round-4 champion skeleton (measured 61.0 us QKV,
// best of 5 schedule variants r4-r8; pre-commitment: no further schedule
// surgery). 2-barrier counted-vmcnt double buffer:
//   vmcnt(PW) -> bar -> ds_read+MFMA -> lgkm0 -> bar -> issue tile kt+2.
// NEW: optional split-K (out-projection): 2 K-halves, 2x blocks (2/CU),
// fp32 atomicAdd into zeroed C; bias added by the ks==0 split only.
// Rationale: out-proj does 8.6 GF as a lone dispatch in the same latency
// regime as QKV — halving the serial K-chain and doubling blocks/CU attacks
// the actual limiter (per-step latency, not throughput).
// ---------------------------------------------------------------------------
struct GemmP {
    const unsigned short* A;
    const unsigned short* Bt;
    const float* bias;
    void* C;
    int N, K, ctShift, biasByRow;
    float scale;
};
struct Gemm3 { GemmP p[3]; };

template <typename OutT, int MR, int NC, bool SPLITK>
__device__ __forceinline__ void gemm_body(const Gemm3& g)
{
    constexpr int AM    = MR / 2;            // per-wave row fragments
    constexpr int NCW   = NC / 4;            // per-wave column fragments
    constexpr int NBLK  = 2 * MR + 2 * NC;   // 512-short staging blocks/buffer
    constexpr int PW    = NBLK / 8;          // staging loads per wave per K-step
    constexpr int BUFSZ = NBLK * 512;        // shorts per buffer

    __shared__ unsigned short sS[2 * BUFSZ]; // [buf0 | buf1]; A blocks first

    // XCD-aware remap across the whole linear grid (launcher guarantees %8==0)
    const unsigned nx  = gridDim.x;
    const unsigned lin = blockIdx.x + nx * blockIdx.z;
    const unsigned ch  = (nx * gridDim.z) >> 3;
    const unsigned l2  = (lin & 7u) * ch + (lin >> 3);
    const unsigned zz  = l2 / nx;
    const unsigned bid0 = l2 - zz * nx;

    const GemmP p = g.p[zz];
    const unsigned short* __restrict__ A  = p.A;
    const unsigned short* __restrict__ Bt = p.Bt;
    OutT* __restrict__ C = (OutT*)p.C;
    const int K = p.K, N = p.N;

    int ks = 0; unsigned bid = bid0;
    if constexpr (SPLITK) { ks = (int)(bid0 >> 8); bid = bid0 & 255u; }
    const int kbase = SPLITK ? ks * (K >> 1) : 0;
    const int KS    = SPLITK ? (K >> 1) : K;     // K extent of this pass

    const int bx = (int)(bid & ((1u << p.ctShift) - 1u));
    const int by = (int)(bid >> p.ctShift);
    const int row0 = by * (MR * 16);
    const int col0 = bx * (NC * 16);

    const int t    = threadIdx.x;
    const int w    = t >> 6;        // 0..7
    const int lane = t & 63;
    const int ln   = lane & 15;
    const int qg   = lane >> 4;
    const int wm   = w >> 2;        // 0..1  (row halves)
    const int wn   = w & 3;         // 0..3  (col quarters)

    // wave-uniform staging assignments: blocks [0,2*MR) = A, rest = B
    const unsigned short* sp[PW];
    int lo[PW];
#pragma unroll
    for (int i = 0; i < PW; ++i) {
        const int s = w * PW + i;
        if (s < 2 * MR) {
            const int mtg = s >> 1, kc = s & 1;
            sp[i] = A + (size_t)(row0 + mtg * 16 + ln) * K + kbase + kc * 32 + qg * 8;
        } else {
            const int bi = s - 2 * MR;
            const int ntg = bi >> 1, kc = bi & 1;
            sp[i] = Bt + (size_t)(col0 + ntg * 16 + ln) * K + kbase + kc * 32 + qg * 8;
        }
        lo[i] = s * 512;
    }

    f32x4 acc[AM][NCW];
#pragma unroll
    for (int mt = 0; mt < AM; ++mt)
#pragma unroll
        for (int nt = 0; nt < NCW; ++nt) acc[mt][nt] = (f32x4){0.f, 0.f, 0.f, 0.f};

    const int NT = KS / 64;

    // ---- prologue: tiles 0 and 1 in flight ----
#pragma unroll
    for (int i = 0; i < PW; ++i) g2lds16(sp[i], &sS[lo[i]]);
#pragma unroll
    for (int i = 0; i < PW; ++i) g2lds16(sp[i] + 64, &sS[BUFSZ + lo[i]]);

    int curOff = 0;
    for (int kt = 0; kt < NT; ++kt) {
        if (kt < NT - 1) s_wait_vmcnt<PW>();
        else             s_wait_vmcnt<0>();
        s_bar();

        const unsigned short* bufA = &sS[curOff];
        const unsigned short* bufB = &sS[curOff + 2 * MR * 512];
#pragma unroll
        for (int kc = 0; kc < 2; ++kc) {
            bf16x8 aF[AM], bF[NCW];
#pragma unroll
            for (int mt = 0; mt < AM; ++mt)
                aF[mt] = *(const bf16x8*)&bufA[(((wm * AM + mt) * 2) + kc) * 512 + lane * 8];
#pragma unroll
            for (int n2 = 0; n2 < NCW; ++n2)
                bF[n2] = *(const bf16x8*)&bufB[(((wn * NCW + n2) * 2) + kc) * 512 + lane * 8];
#pragma unroll
            for (int mt = 0; mt < AM; ++mt)
#pragma unroll
                for (int n2 = 0; n2 < NCW; ++n2)
                    acc[mt][n2] = __builtin_amdgcn_mfma_f32_16x16x32_bf16(
                        aF[mt], bF[n2], acc[mt][n2], 0, 0, 0);
        }

        s_wait_lgkm0();
        s_bar();

        if (kt + 2 < NT) {
            const int koff = (kt + 2) * 64;
#pragma unroll
            for (int i = 0; i < PW; ++i)
                g2lds16(sp[i] + koff, &sS[curOff + lo[i]]);
        }
        curOff ^= BUFSZ;
    }

    float bcol[NCW], brow[AM][4];
    if (!p.biasByRow) {
#pragma unroll
        for (int n2 = 0; n2 < NCW; ++n2)
            bcol[n2] = p.bias[col0 + (wn * NCW + n2) * 16 + ln];
    } else {
#pragma unroll
        for (int mt = 0; mt < AM; ++mt)
#pragma unroll
            for (int r = 0; r < 4; ++r)
                brow[mt][r] = p.bias[row0 + wm * (AM * 16) + mt * 16 + qg * 4 + r];
    }
    const bool addBias = !SPLITK || (ks == 0);

#pragma unroll
    for (int mt = 0; mt < AM; ++mt)
#pragma unroll
        for (int n2 = 0; n2 < NCW; ++n2)
#pragma unroll
            for (int r = 0; r < 4; ++r) {
                int row = row0 + wm * (AM * 16) + mt * 16 + qg * 4 + r;
                int col = col0 + (wn * NCW + n2) * 16 + ln;
                float bb = p.biasByRow ? brow[mt][r] : bcol[n2];
                float vv = (acc[mt][n2][r] + (addBias ? bb : 0.f)) * p.scale;
                if constexpr (SPLITK) atomicAdd((float*)&C[(size_t)row * N + col], vv);
                else                  store_out(&C[(size_t)row * N + col], vv);
            }
}

// separately-named shells so rocprof shows QKV and out-proj independently
__global__ __launch_bounds__(512, 2) void gemm_qkv_kernel(Gemm3 g)
{
    gemm_body<unsigned short, 16, 16, false>(g);
}
__global__ __launch_bounds__(512, 2) void gemm_out_kernel(Gemm3 g)
{
    gemm_body<float, 8, 8, true>(g);
}

// ---------------------------------------------------------------------------
// Flash attention (round-10 structure, unchanged): swapped QK^T, lane-local
// softmax, in-register P exchange; no sP, LDS 40 KB.
// ---------------------------------------------------------------------------
#define BR 64
#define BC 64

__global__ __launch_bounds__(256) void attn_mfma_kernel(
    const unsigned short* __restrict__ Qg, const unsigned short* __restrict__ Kg,
    const unsigned short* __restrict__ VT, unsigned short* __restrict__ O)
{
    __shared__ unsigned short sK[2][8 * 512];   // 16 KB
    __shared__ unsigned short sV[2][8 * 512];   // 16 KB
    __shared__ unsigned short sQ[8 * 512];      // 8 KB

    const int t    = threadIdx.x;
    const int w    = t >> 6;
    const int lane = t & 63;
    const int ln   = lane & 15;
    const int qg   = lane >> 4;

    const int id  = blockIdx.x;
    const int bh  = id & 31;
    const int qt  = (SEQ / BR - 1) - (id >> 5);   // heavy tiles first
    const int b   = bh >> 4;
    const int h   = bh & 15;
    const int qi0 = qt * BR;

    const size_t rowbase = (size_t)b * SEQ;
    const size_t colbase = (size_t)h * DK;

    // ---- stage Q + K/V tile 0 (buf 0) ----
#pragma unroll
    for (int i = 0; i < 2; ++i) {
        const int s = w * 2 + i;
        const int nt = s >> 1, kc = s & 1;
        g2lds16(Qg + (rowbase + qi0 + w * 16 + ln) * DMODEL + colbase + i * 32 + qg * 8,
                &sQ[s * 512]);
        g2lds16(Kg + (rowbase + nt * 16 + ln) * DMODEL + colbase + kc * 32 + qg * 8,
                &sK[0][s * 512]);
        g2lds16(VT + (size_t)(colbase + nt * 16 + ln) * MTOK + rowbase + kc * 32 + qg * 8,
                &sV[0][s * 512]);
    }
    __syncthreads();

    // Q as B-fragment: lane holds Q[q=w*16+ln][d=kc*32+qg*8+j]
    bf16x8 aq[2];
#pragma unroll
    for (int kc = 0; kc < 2; ++kc)
        aq[kc] = *(const bf16x8*)&sQ[(w * 2 + kc) * 512 + lane * 8];

    f32x4 ofrag[4];
#pragma unroll
    for (int nt = 0; nt < 4; ++nt) ofrag[nt] = (f32x4){0.f, 0.f, 0.f, 0.f};
    float osum_p = 0.f;          // per-lane partial denom (own k-slice of q=ln)
    float m_run  = -3.0e38f;     // per-lane running max for q=ln

    // bpermute source lanes for the P-fragment exchange
    const int laneA = ((2 * qg) & 3) * 16 + ln;
    const int laneB = ((2 * qg + 1) & 3) * 16 + ln;
    const bool hiSel = (qg >> 1) & 1;

    const int ntiles = qt + 1;
    for (int jt = 0; jt < ntiles; ++jt) {
        const int cur = jt & 1;

        // ---- prefetch tile jt+1 into the alternate buffer ----
        if (jt + 1 < ntiles) {
            const int j1 = (jt + 1) * BC;
            const int nb = cur ^ 1;
#pragma unroll
            for (int i = 0; i < 2; ++i) {
                const int s = w * 2 + i;
                const int nt = s >> 1, kc = s & 1;
                g2lds16(Kg + (rowbase + j1 + nt * 16 + ln) * DMODEL + colbase + kc * 32 + qg * 8,
                        &sK[nb][s * 512]);
                g2lds16(VT + (size_t)(colbase + nt * 16 + ln) * MTOK + rowbase + j1 + kc * 32 + qg * 8,
                        &sV[nb][s * 512]);
            }
        }

        // ---- S^T = K Q^T (scores pre-scaled by 0.125*log2e) ----
        // sf[nt][r] = S[q=ln][k=nt*16+qg*4+r]
        f32x4 sf[4];
#pragma unroll
        for (int nt = 0; nt < 4; ++nt) {
            f32x4 a2 = (f32x4){0.f, 0.f, 0.f, 0.f};
#pragma unroll
            for (int kc = 0; kc < 2; ++kc) {
                bf16x8 bk = *(const bf16x8*)&sK[cur][(nt * 2 + kc) * 512 + lane * 8];
                a2 = __builtin_amdgcn_mfma_f32_16x16x32_bf16(bk, aq[kc], a2, 0, 0, 0);
            }
            sf[nt] = a2;
        }

        // ---- causal mask (diagonal tile only): k_local > q_local ----
        if (jt == ntiles - 1) {
            const int qloc = w * 16 + ln;
#pragma unroll
            for (int nt = 0; nt < 4; ++nt)
#pragma unroll
                for (int r = 0; r < 4; ++r)
                    if (nt * 16 + qg * 4 + r > qloc) sf[nt][r] = -1.0e30f;
        }

        // ---- online softmax, q-local: scalar m/alpha per lane ----
        float pmax = sf[0][0];
#pragma unroll
        for (int nt = 0; nt < 4; ++nt)
#pragma unroll
            for (int r = 0; r < 4; ++r) pmax = fmaxf(pmax, sf[nt][r]);
        pmax = fmaxf(pmax, __shfl_xor(pmax, 16));
        pmax = fmaxf(pmax, __shfl_xor(pmax, 32));

        const float mn = fmaxf(m_run, pmax);
        const float al = exp2f(m_run - mn);
        m_run = mn;

        float pv[4][4];
        float lsum = 0.f;
#pragma unroll
        for (int nt = 0; nt < 4; ++nt)
#pragma unroll
            for (int r = 0; r < 4; ++r) {
                float e = exp2f(sf[nt][r] - mn);
                pv[nt][r] = e;
                lsum += e;
            }
        osum_p = osum_p * al + lsum;

        // rescale O accumulator rows (row q = qg*4+r needs alpha from lane q)
        float alr[4];
#pragma unroll
        for (int r = 0; r < 4; ++r) alr[r] = __shfl(al, qg * 4 + r);
#pragma unroll
        for (int nt = 0; nt < 4; ++nt)
#pragma unroll
            for (int r = 0; r < 4; ++r) ofrag[nt][r] *= alr[r];

        // ---- pack P to bf16 pairs, exchange into PV A-fragments ----
        unsigned pk0[2], pk1[2], pk2[2], pk3[2];
#pragma unroll
        for (int rr = 0; rr < 2; ++rr) {
            pk0[rr] = cvt_pk_bf16(pv[0][2 * rr], pv[0][2 * rr + 1]);
            pk1[rr] = cvt_pk_bf16(pv[1][2 * rr], pv[1][2 * rr + 1]);
            pk2[rr] = cvt_pk_bf16(pv[2][2 * rr], pv[2][2 * rr + 1]);
            pk3[rr] = cvt_pk_bf16(pv[3][2 * rr], pv[3][2 * rr + 1]);
        }
        union { bf16x8 v; unsigned u[4]; } ap[2];
        {
            unsigned s0, s1;
            s0 = (unsigned)__shfl((int)pk0[0], laneA); s1 = (unsigned)__shfl((int)pk1[0], laneA);
            ap[0].u[0] = hiSel ? s1 : s0;
            s0 = (unsigned)__shfl((int)pk0[1], laneA); s1 = (unsigned)__shfl((int)pk1[1], laneA);
            ap[0].u[1] = hiSel ? s1 : s0;
            s0 = (unsigned)__shfl((int)pk0[0], laneB); s1 = (unsigned)__shfl((int)pk1[0], laneB);
            ap[0].u[2] = hiSel ? s1 : s0;
            s0 = (unsigned)__shfl((int)pk0[1], laneB); s1 = (unsigned)__shfl((int)pk1[1], laneB);
            ap[0].u[3] = hiSel ? s1 : s0;
            s0 = (unsigned)__shfl((int)pk2[0], laneA); s1 = (unsigned)__shfl((int)pk3[0], laneA);
            ap[1].u[0] = hiSel ? s1 : s0;
            s0 = (unsigned)__shfl((int)pk2[1], laneA); s1 = (unsigned)__shfl((int)pk3[1], laneA);
            ap[1].u[1] = hiSel ? s1 : s0;
            s0 = (unsigned)__shfl((int)pk2[0], laneB); s1 = (unsigned)__shfl((int)pk3[0], laneB);
            ap[1].u[2] = hiSel ? s1 : s0;
            s0 = (unsigned)__shfl((int)pk2[1], laneB); s1 = (unsigned)__shfl((int)pk3[1], laneB);
            ap[1].u[3] = hiSel ? s1 : s0;
        }

        // ---- O += P V ----
#pragma unroll
        for (int nt = 0; nt < 4; ++nt) {
#pragma unroll
            for (int kc = 0; kc < 2; ++kc) {
                bf16x8 bv = *(const bf16x8*)&sV[cur][(nt * 2 + kc) * 512 + lane * 8];
                ofrag[nt] = __builtin_amdgcn_mfma_f32_16x16x32_bf16(ap[kc].v, bv, ofrag[nt], 0, 0, 0);
            }
        }

        __syncthreads();    // publish prefetched tile; protect cur for overwrite
    }

    // ---- epilogue: finish denom across k-slices, normalize, write bf16 ----
    float osum = osum_p + __shfl_xor(osum_p, 16);
    osum += __shfl_xor(osum, 32);
    const float invq = 1.0f / osum;     // lane's q = ln
    float inv[4];
#pragma unroll
    for (int r = 0; r < 4; ++r) inv[r] = __shfl(invq, qg * 4 + r);
#pragma unroll
    for (int nt = 0; nt < 4; ++nt)
#pragma unroll
        for (int r = 0; r < 4; ++r) {
            int gq = qi0 + w * 16 + qg * 4 + r;
            O[(rowbase + gq) * DMODEL + colbase + nt * 16 + ln] =
                f2bf(ofrag[nt][r] * inv[r]);
        }
}

// ---------------------------------------------------------------------------
extern "C" void kernel_launch(void* const* d_in, const int* in_sizes, int n_in,
                              void* d_out, int out_size, void* d_ws, size_t ws_size,
                              hipStream_t stream)
{
    const float* q  = (const float*)d_in[0];
    const float* k  = (const float*)d_in[1];
    const float* v  = (const float*)d_in[2];
    // d_in[3] = mask (int32 tril) — causality applied analytically (j<=i).
    const float* wq = (const float*)d_in[4];
    const float* bq = (const float*)d_in[5];
    const float* wk = (const float*)d_in[6];
    const float* bk = (const float*)d_in[7];
    const float* wv = (const float*)d_in[8];
    const float* bv = (const float*)d_in[9];
    const float* wo = (const float*)d_in[10];
    const float* bo = (const float*)d_in[11];
    float* out = (float*)d_out;

    const size_t mat  = (size_t)MTOK * DMODEL;     // 4M elements
    const size_t wmat = (size_t)DMODEL * DMODEL;   // 1M elements
    unsigned short* Abq = (unsigned short*)d_ws;   // bf16 activations
    unsigned short* Abk = Abq + mat;
    unsigned short* Abv = Abk + mat;
    unsigned short* WtQ = Abv + mat;               // bf16 transposed weights
    unsigned short* WtK = WtQ + wmat;
    unsigned short* WtV = WtK + wmat;
    unsigned short* WtO = WtV + wmat;
    unsigned short* Qb  = WtO + wmat;              // bf16 Q proj (pre-scaled)
    unsigned short* Kb  = Qb + mat;                // bf16 K proj
    unsigned short* VT  = Kb + mat;                // bf16 V proj, TRANSPOSED [D][MTOK]
    unsigned short* CTX = VT + mat;                // bf16 attention output

    // zero the fp32 output for the split-K atomic accumulation (graph-safe)
    hipMemsetAsync(out, 0, mat * sizeof(float), stream);

    // merged preprocessing: cvt q/k/v (z 0-2) + 4 weight transposes (z 3-4)
    cvtw_kernel<<<dim3(2048, 1, 5), 256, 0, stream>>>(
        q, k, v, Abq, Abk, Abv, wq, wk, wv, wo, WtQ, WtK, WtV, WtO, (int)mat);

    // fused projections: z0=Q (pre-scaled by 0.125*log2e), z1=K, z2=V transposed.
    // 256x256 tiles: z0/z1: 16x4 = 64 blocks (ctShift=2); z2 (swapped, C=VT
    // [1024 x 4096]): 4x16 = 64 blocks (ctShift=4). Total 192 (%8==0).
    const float qscale = 0.125f * 1.44269504088896f;
    Gemm3 g;
    g.p[0] = (GemmP){Abq, WtQ, bq, (void*)Qb, DMODEL, DMODEL, 2, 0, qscale};
    g.p[1] = (GemmP){Abk, WtK, bk, (void*)Kb, DMODEL, DMODEL, 2, 0, 1.0f};
    g.p[2] = (GemmP){WtV, Abv, bv, (void*)VT, MTOK,   DMODEL, 4, 1, 1.0f};  // swapped operands
    gemm_qkv_kernel<<<dim3(64, 1, 3), 512, 0, stream>>>(g);

    attn_mfma_kernel<<<BATCH * NHEAD * (SEQ / BR), 256, 0, stream>>>(Qb, Kb, VT, CTX);

    // output projection: split-K=2, 128x128 tiles -> 2 x 256 = 512 blocks
    // (2/CU), fp32 atomicAdd into zeroed out; bias added by ks==0 split.
    Gemm3 go;
    go.p[0] = (GemmP){CTX, WtO, bo, (void*)out, DMODEL, DMODEL, 3, 0, 1.0f};
    go.p[1] = go.p[0];
    go.p[2] = go.p[0];
    gemm_out_kernel<<<dim3(512, 1, 1), 512, 0, stream>>>(go);
}

// Round 10
// 262.102 us; speedup vs baseline: 1.0803x; 1.0672x over previous
//
#include <hip/hip_runtime.h>
#include <hip/hip_bf16.h>

// Problem constants (from reference)
#define BATCH 2
#define SEQ   2048
#define DMODEL 1024
#define NHEAD 16
#define DK    64
#define MTOK  (BATCH * SEQ)      // 4096 token rows

typedef __attribute__((ext_vector_type(8))) short bf16x8;   // 8 bf16 in 4 VGPRs
typedef __attribute__((ext_vector_type(4))) float f32x4;    // MFMA 16x16 accumulator

// float -> bf16 bits, round-to-nearest-even
__device__ __forceinline__ unsigned short f2bf(float x) {
    unsigned u = __float_as_uint(x);
    u = (u + 0x7FFFu + ((u >> 16) & 1u)) >> 16;
    return (unsigned short)u;
}

__device__ __forceinline__ void store_out(float* p, float v)          { *p = v; }
__device__ __forceinline__ void store_out(unsigned short* p, float v) { *p = f2bf(v); }

// packed f32x2 -> bf16x2 (RNE, same rounding as f2bf), lo = x, hi = y
__device__ __forceinline__ unsigned cvt_pk_bf16(float x, float y) {
    unsigned d;
    asm("v_cvt_pk_bf16_f32 %0, %1, %2" : "=v"(d) : "v"(x), "v"(y));
    return d;
}

// async global->LDS, 16 B per lane; LDS dest = wave-uniform base + lane*16.
__device__ __forceinline__ void g2lds16(const void* g, void* l) {
    __builtin_amdgcn_global_load_lds(
        (const __attribute__((address_space(1))) void*)g,
        (__attribute__((address_space(3))) void*)l, 16, 0, 0);
}

template <int N>
__device__ __forceinline__ void s_wait_vmcnt() {
    asm volatile("s_waitcnt vmcnt(%0)" :: "n"(N) : "memory");
}
__device__ __forceinline__ void s_wait_lgkm0() {
    asm volatile("s_waitcnt lgkmcnt(0)" ::: "memory");
}
__device__ __forceinline__ void s_bar() {
    asm volatile("s_barrier" ::: "memory");
}

// ---------------------------------------------------------------------------
// Merged preprocessing, one launch:
//   z 0..2 : fp32 -> bf16 convert of q/k/v (2048 x-blocks, 8 elems/thread)
//   z 3..4 : transpose+convert 2 weight matrices each (x encodes wgt+tile)
// ---------------------------------------------------------------------------
__global__ __launch_bounds__(256) void cvtw_kernel(
    const float* __restrict__ q, const float* __restrict__ k,
    const float* __restrict__ v,
    unsigned short* __restrict__ dq, unsigned short* __restrict__ dk,
    unsigned short* __restrict__ dv,
    const float* __restrict__ w0, const float* __restrict__ w1,
    const float* __restrict__ w2, const float* __restrict__ w3,
    unsigned short* __restrict__ t0, unsigned short* __restrict__ t1,
    unsigned short* __restrict__ t2, unsigned short* __restrict__ t3, int n)
{
    __shared__ float tile[32][33];
    if (blockIdx.z < 3) {
        const float* src; unsigned short* dst;
        switch (blockIdx.z) {
            case 0:  src = q; dst = dq; break;
            case 1:  src = k; dst = dk; break;
            default: src = v; dst = dv; break;
        }
        int i = (blockIdx.x * 256 + threadIdx.x) * 8;
        if (i >= n) return;
        float4 a = *(const float4*)(src + i);
        float4 b = *(const float4*)(src + i + 4);
        union { unsigned short s[8]; uint4 u; } o;
        o.s[0] = f2bf(a.x); o.s[1] = f2bf(a.y); o.s[2] = f2bf(a.z); o.s[3] = f2bf(a.w);
        o.s[4] = f2bf(b.x); o.s[5] = f2bf(b.y); o.s[6] = f2bf(b.z); o.s[7] = f2bf(b.w);
        *(uint4*)(dst + i) = o.u;
    } else {
        const int wi = (blockIdx.z - 3) * 2 + (blockIdx.x >> 10);
        const float* W; unsigned short* T;
        switch (wi) {
            case 0:  W = w0; T = t0; break;
            case 1:  W = w1; T = t1; break;
            case 2:  W = w2; T = t2; break;
            default: W = w3; T = t3; break;
        }
        const int ti = blockIdx.x & 1023;
        const int n0 = (ti & 31) * 32, k0 = (ti >> 5) * 32;
        const int t  = threadIdx.x;
        const int r  = t >> 3;          // 0..31
        const int c4 = (t & 7) * 4;     // 0..28

        float4 vv = *(const float4*)&W[(size_t)(k0 + r) * DMODEL + n0 + c4];
        tile[r][c4 + 0] = vv.x; tile[r][c4 + 1] = vv.y;
        tile[r][c4 + 2] = vv.z; tile[r][c4 + 3] = vv.w;
        __syncthreads();

        union { unsigned short s[4]; uint2 u; } o;
#pragma unroll
        for (int u = 0; u < 4; ++u) o.s[u] = f2bf(tile[c4 + u][r]);
        *(uint2*)&T[(size_t)(n0 + r) * DMODEL + k0 + c4] = o.u;
    }
}

// ---------------------------------------------------------------------------
// MFMA GEMM = round-4 champion skeleton (measured 60-61 us QKV; best of 5
// schedule variants r4-r8; split-K/atomics regressed +20 us in r9 — removed).
// 2-barrier counted-vmcnt double buffer:
//   vmcnt(PW) -> bar -> ds_read+MFMA -> lgkm0 -> bar -> issue tile kt+2.
//  - QKV: MR=16,NC=16 (256x256, 192 blocks); outproj: MR=8,NC=8 (128x128, 256)
//  - wave grid 2(M) x 4(N); XCD-aware bijective remap (grid%8==0).
// ---------------------------------------------------------------------------
struct GemmP {
    const unsigned short* A;
    const unsigned short* Bt;
    const float* bias;
    void* C;
    int N, K, ctShift, biasByRow;
    float scale;
};
struct Gemm3 { GemmP p[3]; };

template <typename OutT, int MR, int NC>
__device__ __forceinline__ void gemm_body(const Gemm3& g)
{
    constexpr int AM    = MR / 2;            // per-wave row fragments
    constexpr int NCW   = NC / 4;            // per-wave column fragments
    constexpr int NBLK  = 2 * MR + 2 * NC;   // 512-short staging blocks/buffer
    constexpr int PW    = NBLK / 8;          // staging loads per wave per K-step
    constexpr int BUFSZ = NBLK * 512;        // shorts per buffer

    __shared__ unsigned short sS[2 * BUFSZ]; // [buf0 | buf1]; A blocks first

    // XCD-aware remap across the whole linear grid (launcher guarantees %8==0)
    const unsigned nx  = gridDim.x;
    const unsigned lin = blockIdx.x + nx * blockIdx.z;
    const unsigned ch  = (nx * gridDim.z) >> 3;
    const unsigned l2  = (lin & 7u) * ch + (lin >> 3);
    const unsigned zz  = l2 / nx;
    const unsigned bid = l2 - zz * nx;

    const GemmP p = g.p[zz];
    const unsigned short* __restrict__ A  = p.A;
    const unsigned short* __restrict__ Bt = p.Bt;
    OutT* __restrict__ C = (OutT*)p.C;
    const int K = p.K, N = p.N;

    const int bx = (int)(bid & ((1u << p.ctShift) - 1u));
    const int by = (int)(bid >> p.ctShift);
    const int row0 = by * (MR * 16);
    const int col0 = bx * (NC * 16);

    const int t    = threadIdx.x;
    const int w    = t >> 6;        // 0..7
    const int lane = t & 63;
    const int ln   = lane & 15;
    const int qg   = lane >> 4;
    const int wm   = w >> 2;        // 0..1  (row halves)
    const int wn   = w & 3;         // 0..3  (col quarters)

    // wave-uniform staging assignments: blocks [0,2*MR) = A, rest = B
    const unsigned short* sp[PW];
    int lo[PW];
#pragma unroll
    for (int i = 0; i < PW; ++i) {
        const int s = w * PW + i;
        if (s < 2 * MR) {
            const int mtg = s >> 1, kc = s & 1;
            sp[i] = A + (size_t)(row0 + mtg * 16 + ln) * K + kc * 32 + qg * 8;
        } else {
            const int bi = s - 2 * MR;
            const int ntg = bi >> 1, kc = bi & 1;
            sp[i] = Bt + (size_t)(col0 + ntg * 16 + ln) * K + kc * 32 + qg * 8;
        }
        lo[i] = s * 512;
    }

    f32x4 acc[AM][NCW];
#pragma unroll
    for (int mt = 0; mt < AM; ++mt)
#pragma unroll
        for (int nt = 0; nt < NCW; ++nt) acc[mt][nt] = (f32x4){0.f, 0.f, 0.f, 0.f};

    const int NT = K / 64;

    // ---- prologue: tiles 0 and 1 in flight ----
#pragma unroll
    for (int i = 0; i < PW; ++i) g2lds16(sp[i], &sS[lo[i]]);
#pragma unroll
    for (int i = 0; i < PW; ++i) g2lds16(sp[i] + 64, &sS[BUFSZ + lo[i]]);

    int curOff = 0;
    for (int kt = 0; kt < NT; ++kt) {
        if (kt < NT - 1) s_wait_vmcnt<PW>();
        else             s_wait_vmcnt<0>();
        s_bar();

        const unsigned short* bufA = &sS[curOff];
        const unsigned short* bufB = &sS[curOff + 2 * MR * 512];
#pragma unroll
        for (int kc = 0; kc < 2; ++kc) {
            bf16x8 aF[AM], bF[NCW];
#pragma unroll
            for (int mt = 0; mt < AM; ++mt)
                aF[mt] = *(const bf16x8*)&bufA[(((wm * AM + mt) * 2) + kc) * 512 + lane * 8];
#pragma unroll
            for (int n2 = 0; n2 < NCW; ++n2)
                bF[n2] = *(const bf16x8*)&bufB[(((wn * NCW + n2) * 2) + kc) * 512 + lane * 8];
#pragma unroll
            for (int mt = 0; mt < AM; ++mt)
#pragma unroll
                for (int n2 = 0; n2 < NCW; ++n2)
                    acc[mt][n2] = __builtin_amdgcn_mfma_f32_16x16x32_bf16(
                        aF[mt], bF[n2], acc[mt][n2], 0, 0, 0);
        }

        s_wait_lgkm0();
        s_bar();

        if (kt + 2 < NT) {
            const int koff = (kt + 2) * 64;
#pragma unroll
            for (int i = 0; i < PW; ++i)
                g2lds16(sp[i] + koff, &sS[curOff + lo[i]]);
        }
        curOff ^= BUFSZ;
    }

    float bcol[NCW], brow[AM][4];
    if (!p.biasByRow) {
#pragma unroll
        for (int n2 = 0; n2 < NCW; ++n2)
            bcol[n2] = p.bias[col0 + (wn * NCW + n2) * 16 + ln];
    } else {
#pragma unroll
        for (int mt = 0; mt < AM; ++mt)
#pragma unroll
            for (int r = 0; r < 4; ++r)
                brow[mt][r] = p.bias[row0 + wm * (AM * 16) + mt * 16 + qg * 4 + r];
    }

#pragma unroll
    for (int mt = 0; mt < AM; ++mt)
#pragma unroll
        for (int n2 = 0; n2 < NCW; ++n2)
#pragma unroll
            for (int r = 0; r < 4; ++r) {
                int row = row0 + wm * (AM * 16) + mt * 16 + qg * 4 + r;
                int col = col0 + (wn * NCW + n2) * 16 + ln;
                float bb = p.biasByRow ? brow[mt][r] : bcol[n2];
                store_out(&C[(size_t)row * N + col], (acc[mt][n2][r] + bb) * p.scale);
            }
}

// separately-named shells so rocprof shows QKV and out-proj independently
__global__ __launch_bounds__(512, 2) void gemm_qkv_kernel(Gemm3 g)
{
    gemm_body<unsigned short, 16, 16>(g);
}
__global__ __launch_bounds__(512, 2) void gemm_out_kernel(Gemm3 g)
{
    gemm_body<float, 8, 8>(g);
}

// ---------------------------------------------------------------------------
// Flash attention, round-16: BR=128 (8 waves, 512 threads). Each staged K/V
// tile now serves 128 q-rows (was 64) -> per-CU K/V staging traffic and
// block count halve (512 blocks, 2/CU, 48 KB LDS, same 16 waves/CU).
// Per-wave structure (swapped QK^T, lane-local softmax, in-register P
// exchange) is UNCHANGED — only staging indexing (1 K + 1 V issue per wave),
// ntiles = 2*qt+2, and a global-coordinate causal mask on the last two
// tiles differ. Fully-masked sub-tiles for low waves compute zeros (~3%
// waste) to keep barrier counts uniform.
// ---------------------------------------------------------------------------
#define BR 128
#define BC 64

__global__ __launch_bounds__(512) void attn_mfma_kernel(
    const unsigned short* __restrict__ Qg, const unsigned short* __restrict__ Kg,
    const unsigned short* __restrict__ VT, unsigned short* __restrict__ O)
{
    __shared__ unsigned short sK[2][8 * 512];   // 16 KB (64 kv-rows x 64 d)
    __shared__ unsigned short sV[2][8 * 512];   // 16 KB
    __shared__ unsigned short sQ[16 * 512];     // 16 KB (128 q-rows x 64 d)

    const int t    = threadIdx.x;
    const int w    = t >> 6;        // 0..7
    const int lane = t & 63;
    const int ln   = lane & 15;
    const int qg   = lane >> 4;

    const int id  = blockIdx.x;
    const int bh  = id & 31;
    const int qt  = (SEQ / BR - 1) - (id >> 5);   // heavy tiles first (0..15)
    const int b   = bh >> 4;
    const int h   = bh & 15;
    const int qi0 = qt * BR;

    const size_t rowbase = (size_t)b * SEQ;
    const size_t colbase = (size_t)h * DK;

    const int snt = w >> 1, skc = w & 1;          // this wave's K/V slot

    // ---- stage Q (16 blocks, 2/wave) + K/V tile 0 (8 blocks, 1/wave each) ----
#pragma unroll
    for (int i = 0; i < 2; ++i) {
        const int s = w * 2 + i;
        g2lds16(Qg + (rowbase + qi0 + w * 16 + ln) * DMODEL + colbase + i * 32 + qg * 8,
                &sQ[s * 512]);
    }
    g2lds16(Kg + (rowbase + snt * 16 + ln) * DMODEL + colbase + skc * 32 + qg * 8,
            &sK[0][w * 512]);
    g2lds16(VT + (size_t)(colbase + snt * 16 + ln) * MTOK + rowbase + skc * 32 + qg * 8,
            &sV[0][w * 512]);
    __syncthreads();

    // Q as B-fragment: lane holds Q[q=w*16+ln][d=kc*32+qg*8+j]
    bf16x8 aq[2];
#pragma unroll
    for (int kc = 0; kc < 2; ++kc)
        aq[kc] = *(const bf16x8*)&sQ[(w * 2 + kc) * 512 + lane * 8];

    f32x4 ofrag[4];
#pragma unroll
    for (int nt = 0; nt < 4; ++nt) ofrag[nt] = (f32x4){0.f, 0.f, 0.f, 0.f};
    float osum_p = 0.f;          // per-lane partial denom (own k-slice of q=ln)
    float m_run  = -3.0e38f;     // per-lane running max for q=ln

    // bpermute source lanes for the P-fragment exchange
    const int laneA = ((2 * qg) & 3) * 16 + ln;
    const int laneB = ((2 * qg + 1) & 3) * 16 + ln;
    const bool hiSel = (qg >> 1) & 1;

    const int ntiles = 2 * qt + 2;               // k-tiles of 64 covering [0, qi0+128)
    for (int jt = 0; jt < ntiles; ++jt) {
        const int cur = jt & 1;

        // ---- prefetch tile jt+1 into the alternate buffer ----
        if (jt + 1 < ntiles) {
            const int j1 = (jt + 1) * BC;
            const int nb = cur ^ 1;
            g2lds16(Kg + (rowbase + j1 + snt * 16 + ln) * DMODEL + colbase + skc * 32 + qg * 8,
                    &sK[nb][w * 512]);
            g2lds16(VT + (size_t)(colbase + snt * 16 + ln) * MTOK + rowbase + j1 + skc * 32 + qg * 8,
                    &sV[nb][w * 512]);
        }

        // ---- S^T = K Q^T (scores pre-scaled by 0.125*log2e) ----
        // sf[nt][r] = S[q=ln][k=nt*16+qg*4+r]
        f32x4 sf[4];
#pragma unroll
        for (int nt = 0; nt < 4; ++nt) {
            f32x4 a2 = (f32x4){0.f, 0.f, 0.f, 0.f};
#pragma unroll
            for (int kc = 0; kc < 2; ++kc) {
                bf16x8 bk = *(const bf16x8*)&sK[cur][(nt * 2 + kc) * 512 + lane * 8];
                a2 = __builtin_amdgcn_mfma_f32_16x16x32_bf16(bk, aq[kc], a2, 0, 0, 0);
            }
            sf[nt] = a2;
        }

        // ---- causal mask (last two tiles may cross the diagonal) ----
        if (jt >= ntiles - 2) {
            const int qglob = qi0 + w * 16 + ln;     // this lane's q row
            const int kb = jt * BC;
#pragma unroll
            for (int nt = 0; nt < 4; ++nt)
#pragma unroll
                for (int r = 0; r < 4; ++r)
                    if (kb + nt * 16 + qg * 4 + r > qglob) sf[nt][r] = -1.0e30f;
        }

        // ---- online softmax, q-local: scalar m/alpha per lane ----
        float pmax = sf[0][0];
#pragma unroll
        for (int nt = 0; nt < 4; ++nt)
#pragma unroll
            for (int r = 0; r < 4; ++r) pmax = fmaxf(pmax, sf[nt][r]);
        pmax = fmaxf(pmax, __shfl_xor(pmax, 16));
        pmax = fmaxf(pmax, __shfl_xor(pmax, 32));

        const float mn = fmaxf(m_run, pmax);
        const float al = exp2f(m_run - mn);
        m_run = mn;

        float pv[4][4];
        float lsum = 0.f;
#pragma unroll
        for (int nt = 0; nt < 4; ++nt)
#pragma unroll
            for (int r = 0; r < 4; ++r) {
                float e = exp2f(sf[nt][r] - mn);
                pv[nt][r] = e;
                lsum += e;
            }
        osum_p = osum_p * al + lsum;

        // rescale O accumulator rows (row q = qg*4+r needs alpha from lane q)
        float alr[4];
#pragma unroll
        for (int r = 0; r < 4; ++r) alr[r] = __shfl(al, qg * 4 + r);
#pragma unroll
        for (int nt = 0; nt < 4; ++nt)
#pragma unroll
            for (int r = 0; r < 4; ++r) ofrag[nt][r] *= alr[r];

        // ---- pack P to bf16 pairs, exchange into PV A-fragments ----
        unsigned pk0[2], pk1[2], pk2[2], pk3[2];
#pragma unroll
        for (int rr = 0; rr < 2; ++rr) {
            pk0[rr] = cvt_pk_bf16(pv[0][2 * rr], pv[0][2 * rr + 1]);
            pk1[rr] = cvt_pk_bf16(pv[1][2 * rr], pv[1][2 * rr + 1]);
            pk2[rr] = cvt_pk_bf16(pv[2][2 * rr], pv[2][2 * rr + 1]);
            pk3[rr] = cvt_pk_bf16(pv[3][2 * rr], pv[3][2 * rr + 1]);
        }
        union { bf16x8 v; unsigned u[4]; } ap[2];
        {
            unsigned s0, s1;
            s0 = (unsigned)__shfl((int)pk0[0], laneA); s1 = (unsigned)__shfl((int)pk1[0], laneA);
            ap[0].u[0] = hiSel ? s1 : s0;
            s0 = (unsigned)__shfl((int)pk0[1], laneA); s1 = (unsigned)__shfl((int)pk1[1], laneA);
            ap[0].u[1] = hiSel ? s1 : s0;
            s0 = (unsigned)__shfl((int)pk0[0], laneB); s1 = (unsigned)__shfl((int)pk1[0], laneB);
            ap[0].u[2] = hiSel ? s1 : s0;
            s0 = (unsigned)__shfl((int)pk0[1], laneB); s1 = (unsigned)__shfl((int)pk1[1], laneB);
            ap[0].u[3] = hiSel ? s1 : s0;
            s0 = (unsigned)__shfl((int)pk2[0], laneA); s1 = (unsigned)__shfl((int)pk3[0], laneA);
            ap[1].u[0] = hiSel ? s1 : s0;
            s0 = (unsigned)__shfl((int)pk2[1], laneA); s1 = (unsigned)__shfl((int)pk3[1], laneA);
            ap[1].u[1] = hiSel ? s1 : s0;
            s0 = (unsigned)__shfl((int)pk2[0], laneB); s1 = (unsigned)__shfl((int)pk3[0], laneB);
            ap[1].u[2] = hiSel ? s1 : s0;
            s0 = (unsigned)__shfl((int)pk2[1], laneB); s1 = (unsigned)__shfl((int)pk3[1], laneB);
            ap[1].u[3] = hiSel ? s1 : s0;
        }

        // ---- O += P V ----
#pragma unroll
        for (int nt = 0; nt < 4; ++nt) {
#pragma unroll
            for (int kc = 0; kc < 2; ++kc) {
                bf16x8 bv = *(const bf16x8*)&sV[cur][(nt * 2 + kc) * 512 + lane * 8];
                ofrag[nt] = __builtin_amdgcn_mfma_f32_16x16x32_bf16(ap[kc].v, bv, ofrag[nt], 0, 0, 0);
            }
        }

        __syncthreads();    // publish prefetched tile; protect cur for overwrite
    }

    // ---- epilogue: finish denom across k-slices, normalize, write bf16 ----
    float osum = osum_p + __shfl_xor(osum_p, 16);
    osum += __shfl_xor(osum, 32);
    const float invq = 1.0f / osum;     // lane's q = ln
    float inv[4];
#pragma unroll
    for (int r = 0; r < 4; ++r) inv[r] = __shfl(invq, qg * 4 + r);
#pragma unroll
    for (int nt = 0; nt < 4; ++nt)
#pragma unroll
        for (int r = 0; r < 4; ++r) {
            int gq = qi0 + w * 16 + qg * 4 + r;
            O[(rowbase + gq) * DMODEL + colbase + nt * 16 + ln] =
                f2bf(ofrag[nt][r] * inv[r]);
        }
}

// ---------------------------------------------------------------------------
extern "C" void kernel_launch(void* const* d_in, const int* in_sizes, int n_in,
                              void* d_out, int out_size, void* d_ws, size_t ws_size,
                              hipStream_t stream)
{
    const float* q  = (const float*)d_in[0];
    const float* k  = (const float*)d_in[1];
    const float* v  = (const float*)d_in[2];
    // d_in[3] = mask (int32 tril) — causality applied analytically (j<=i).
    const float* wq = (const float*)d_in[4];
    const float* bq = (const float*)d_in[5];
    const float* wk = (const float*)d_in[6];
    const float* bk = (const float*)d_in[7];
    const float* wv = (const float*)d_in[8];
    const float* bv = (const float*)d_in[9];
    const float* wo = (const float*)d_in[10];
    const float* bo = (const float*)d_in[11];
    float* out = (float*)d_out;

    const size_t mat  = (size_t)MTOK * DMODEL;     // 4M elements
    const size_t wmat = (size_t)DMODEL * DMODEL;   // 1M elements
    unsigned short* Abq = (unsigned short*)d_ws;   // bf16 activations
    unsigned short* Abk = Abq + mat;
    unsigned short* Abv = Abk + mat;
    unsigned short* WtQ = Abv + mat;               // bf16 transposed weights
    unsigned short* WtK = WtQ + wmat;
    unsigned short* WtV = WtK + wmat;
    unsigned short* WtO = WtV + wmat;
    unsigned short* Qb  = WtO + wmat;              // bf16 Q proj (pre-scaled)
    unsigned short* Kb  = Qb + mat;                // bf16 K proj
    unsigned short* VT  = Kb + mat;                // bf16 V proj, TRANSPOSED [D][MTOK]
    unsigned short* CTX = VT + mat;                // bf16 attention output

    // merged preprocessing: cvt q/k/v (z 0-2) + 4 weight transposes (z 3-4)
    cvtw_kernel<<<dim3(2048, 1, 5), 256, 0, stream>>>(
        q, k, v, Abq, Abk, Abv, wq, wk, wv, wo, WtQ, WtK, WtV, WtO, (int)mat);

    // fused projections: z0=Q (pre-scaled by 0.125*log2e), z1=K, z2=V transposed.
    // 256x256 tiles: z0/z1: 16x4 = 64 blocks (ctShift=2); z2 (swapped, C=VT
    // [1024 x 4096]): 4x16 = 64 blocks (ctShift=4). Total 192 (%8==0).
    const float qscale = 0.125f * 1.44269504088896f;
    Gemm3 g;
    g.p[0] = (GemmP){Abq, WtQ, bq, (void*)Qb, DMODEL, DMODEL, 2, 0, qscale};
    g.p[1] = (GemmP){Abk, WtK, bk, (void*)Kb, DMODEL, DMODEL, 2, 0, 1.0f};
    g.p[2] = (GemmP){WtV, Abv, bv, (void*)VT, MTOK,   DMODEL, 4, 1, 1.0f};  // swapped operands
    gemm_qkv_kernel<<<dim3(64, 1, 3), 512, 0, stream>>>(g);

    // attention: 512 blocks of 512 threads (BR=128, heavy-first)
    attn_mfma_kernel<<<BATCH * NHEAD * (SEQ / BR), 512, 0, stream>>>(Qb, Kb, VT, CTX);

    // output projection: plain 128x128 tiles -> 32x8 = 256 blocks
    Gemm3 go;
    go.p[0] = (GemmP){CTX, WtO, bo, (void*)out, DMODEL, DMODEL, 3, 0, 1.0f};
    go.p[1] = go.p[0];
    go.p[2] = go.p[0];
    gemm_out_kernel<<<dim3(256, 1, 1), 512, 0, stream>>>(go);
}

// Round 11
// 252.737 us; speedup vs baseline: 1.1203x; 1.0371x over previous
//
#include <hip/hip_runtime.h>
#include <hip/hip_bf16.h>

// Problem constants (from reference)
#define BATCH 2
#define SEQ   2048
#define DMODEL 1024
#define NHEAD 16
#define DK    64
#define MTOK  (BATCH * SEQ)      // 4096 token rows

typedef __attribute__((ext_vector_type(8))) short bf16x8;   // 8 bf16 in 4 VGPRs
typedef __attribute__((ext_vector_type(4))) float f32x4;    // MFMA 16x16 accumulator

// float -> bf16 bits, round-to-nearest-even
__device__ __forceinline__ unsigned short f2bf(float x) {
    unsigned u = __float_as_uint(x);
    u = (u + 0x7FFFu + ((u >> 16) & 1u)) >> 16;
    return (unsigned short)u;
}

__device__ __forceinline__ void store_out(float* p, float v)          { *p = v; }
__device__ __forceinline__ void store_out(unsigned short* p, float v) { *p = f2bf(v); }

// packed f32x2 -> bf16x2 (RNE, same rounding as f2bf), lo = x, hi = y
__device__ __forceinline__ unsigned cvt_pk_bf16(float x, float y) {
    unsigned d;
    asm("v_cvt_pk_bf16_f32 %0, %1, %2" : "=v"(d) : "v"(x), "v"(y));
    return d;
}

// async global->LDS, 16 B per lane; LDS dest = wave-uniform base + lane*16.
__device__ __forceinline__ void g2lds16(const void* g, void* l) {
    __builtin_amdgcn_global_load_lds(
        (const __attribute__((address_space(1))) void*)g,
        (__attribute__((address_space(3))) void*)l, 16, 0, 0);
}

template <int N>
__device__ __forceinline__ void s_wait_vmcnt() {
    asm volatile("s_waitcnt vmcnt(%0)" :: "n"(N) : "memory");
}
__device__ __forceinline__ void s_wait_lgkm0() {
    asm volatile("s_waitcnt lgkmcnt(0)" ::: "memory");
}
__device__ __forceinline__ void s_bar() {
    asm volatile("s_barrier" ::: "memory");
}

// ---------------------------------------------------------------------------
// Merged preprocessing, one launch:
//   z 0..2 : fp32 -> bf16 convert of q/k/v (2048 x-blocks, 8 elems/thread)
//   z 3..4 : transpose+convert 2 weight matrices each (x encodes wgt+tile)
// ---------------------------------------------------------------------------
__global__ __launch_bounds__(256) void cvtw_kernel(
    const float* __restrict__ q, const float* __restrict__ k,
    const float* __restrict__ v,
    unsigned short* __restrict__ dq, unsigned short* __restrict__ dk,
    unsigned short* __restrict__ dv,
    const float* __restrict__ w0, const float* __restrict__ w1,
    const float* __restrict__ w2, const float* __restrict__ w3,
    unsigned short* __restrict__ t0, unsigned short* __restrict__ t1,
    unsigned short* __restrict__ t2, unsigned short* __restrict__ t3, int n)
{
    __shared__ float tile[32][33];
    if (blockIdx.z < 3) {
        const float* src; unsigned short* dst;
        switch (blockIdx.z) {
            case 0:  src = q; dst = dq; break;
            case 1:  src = k; dst = dk; break;
            default: src = v; dst = dv; break;
        }
        int i = (blockIdx.x * 256 + threadIdx.x) * 8;
        if (i >= n) return;
        float4 a = *(const float4*)(src + i);
        float4 b = *(const float4*)(src + i + 4);
        union { unsigned short s[8]; uint4 u; } o;
        o.s[0] = f2bf(a.x); o.s[1] = f2bf(a.y); o.s[2] = f2bf(a.z); o.s[3] = f2bf(a.w);
        o.s[4] = f2bf(b.x); o.s[5] = f2bf(b.y); o.s[6] = f2bf(b.z); o.s[7] = f2bf(b.w);
        *(uint4*)(dst + i) = o.u;
    } else {
        const int wi = (blockIdx.z - 3) * 2 + (blockIdx.x >> 10);
        const float* W; unsigned short* T;
        switch (wi) {
            case 0:  W = w0; T = t0; break;
            case 1:  W = w1; T = t1; break;
            case 2:  W = w2; T = t2; break;
            default: W = w3; T = t3; break;
        }
        const int ti = blockIdx.x & 1023;
        const int n0 = (ti & 31) * 32, k0 = (ti >> 5) * 32;
        const int t  = threadIdx.x;
        const int r  = t >> 3;          // 0..31
        const int c4 = (t & 7) * 4;     // 0..28

        float4 vv = *(const float4*)&W[(size_t)(k0 + r) * DMODEL + n0 + c4];
        tile[r][c4 + 0] = vv.x; tile[r][c4 + 1] = vv.y;
        tile[r][c4 + 2] = vv.z; tile[r][c4 + 3] = vv.w;
        __syncthreads();

        union { unsigned short s[4]; uint2 u; } o;
#pragma unroll
        for (int u = 0; u < 4; ++u) o.s[u] = f2bf(tile[c4 + u][r]);
        *(uint2*)&T[(size_t)(n0 + r) * DMODEL + k0 + c4] = o.u;
    }
}

// ---------------------------------------------------------------------------
// MFMA GEMM = round-4 champion skeleton (measured 60-61 us QKV; best of 5
// schedule variants; split-K/atomics regressed +20 us — removed).
// 2-barrier counted-vmcnt double buffer:
//   vmcnt(PW) -> bar -> ds_read+MFMA -> lgkm0 -> bar -> issue tile kt+2.
//  - QKV: MR=16,NC=16 (256x256, 192 blocks); outproj: MR=8,NC=8 (128x128, 256)
//  - wave grid 2(M) x 4(N); XCD-aware bijective remap (grid%8==0).
// ---------------------------------------------------------------------------
struct GemmP {
    const unsigned short* A;
    const unsigned short* Bt;
    const float* bias;
    void* C;
    int N, K, ctShift, biasByRow;
    float scale;
};
struct Gemm3 { GemmP p[3]; };

template <typename OutT, int MR, int NC>
__device__ __forceinline__ void gemm_body(const Gemm3& g)
{
    constexpr int AM    = MR / 2;            // per-wave row fragments
    constexpr int NCW   = NC / 4;            // per-wave column fragments
    constexpr int NBLK  = 2 * MR + 2 * NC;   // 512-short staging blocks/buffer
    constexpr int PW    = NBLK / 8;          // staging loads per wave per K-step
    constexpr int BUFSZ = NBLK * 512;        // shorts per buffer

    __shared__ unsigned short sS[2 * BUFSZ]; // [buf0 | buf1]; A blocks first

    // XCD-aware remap across the whole linear grid (launcher guarantees %8==0)
    const unsigned nx  = gridDim.x;
    const unsigned lin = blockIdx.x + nx * blockIdx.z;
    const unsigned ch  = (nx * gridDim.z) >> 3;
    const unsigned l2  = (lin & 7u) * ch + (lin >> 3);
    const unsigned zz  = l2 / nx;
    const unsigned bid = l2 - zz * nx;

    const GemmP p = g.p[zz];
    const unsigned short* __restrict__ A  = p.A;
    const unsigned short* __restrict__ Bt = p.Bt;
    OutT* __restrict__ C = (OutT*)p.C;
    const int K = p.K, N = p.N;

    const int bx = (int)(bid & ((1u << p.ctShift) - 1u));
    const int by = (int)(bid >> p.ctShift);
    const int row0 = by * (MR * 16);
    const int col0 = bx * (NC * 16);

    const int t    = threadIdx.x;
    const int w    = t >> 6;        // 0..7
    const int lane = t & 63;
    const int ln   = lane & 15;
    const int qg   = lane >> 4;
    const int wm   = w >> 2;        // 0..1  (row halves)
    const int wn   = w & 3;         // 0..3  (col quarters)

    // wave-uniform staging assignments: blocks [0,2*MR) = A, rest = B
    const unsigned short* sp[PW];
    int lo[PW];
#pragma unroll
    for (int i = 0; i < PW; ++i) {
        const int s = w * PW + i;
        if (s < 2 * MR) {
            const int mtg = s >> 1, kc = s & 1;
            sp[i] = A + (size_t)(row0 + mtg * 16 + ln) * K + kc * 32 + qg * 8;
        } else {
            const int bi = s - 2 * MR;
            const int ntg = bi >> 1, kc = bi & 1;
            sp[i] = Bt + (size_t)(col0 + ntg * 16 + ln) * K + kc * 32 + qg * 8;
        }
        lo[i] = s * 512;
    }

    f32x4 acc[AM][NCW];
#pragma unroll
    for (int mt = 0; mt < AM; ++mt)
#pragma unroll
        for (int nt = 0; nt < NCW; ++nt) acc[mt][nt] = (f32x4){0.f, 0.f, 0.f, 0.f};

    const int NT = K / 64;

    // ---- prologue: tiles 0 and 1 in flight ----
#pragma unroll
    for (int i = 0; i < PW; ++i) g2lds16(sp[i], &sS[lo[i]]);
#pragma unroll
    for (int i = 0; i < PW; ++i) g2lds16(sp[i] + 64, &sS[BUFSZ + lo[i]]);

    int curOff = 0;
    for (int kt = 0; kt < NT; ++kt) {
        if (kt < NT - 1) s_wait_vmcnt<PW>();
        else             s_wait_vmcnt<0>();
        s_bar();

        const unsigned short* bufA = &sS[curOff];
        const unsigned short* bufB = &sS[curOff + 2 * MR * 512];
#pragma unroll
        for (int kc = 0; kc < 2; ++kc) {
            bf16x8 aF[AM], bF[NCW];
#pragma unroll
            for (int mt = 0; mt < AM; ++mt)
                aF[mt] = *(const bf16x8*)&bufA[(((wm * AM + mt) * 2) + kc) * 512 + lane * 8];
#pragma unroll
            for (int n2 = 0; n2 < NCW; ++n2)
                bF[n2] = *(const bf16x8*)&bufB[(((wn * NCW + n2) * 2) + kc) * 512 + lane * 8];
#pragma unroll
            for (int mt = 0; mt < AM; ++mt)
#pragma unroll
                for (int n2 = 0; n2 < NCW; ++n2)
                    acc[mt][n2] = __builtin_amdgcn_mfma_f32_16x16x32_bf16(
                        aF[mt], bF[n2], acc[mt][n2], 0, 0, 0);
        }

        s_wait_lgkm0();
        s_bar();

        if (kt + 2 < NT) {
            const int koff = (kt + 2) * 64;
#pragma unroll
            for (int i = 0; i < PW; ++i)
                g2lds16(sp[i] + koff, &sS[curOff + lo[i]]);
        }
        curOff ^= BUFSZ;
    }

    float bcol[NCW], brow[AM][4];
    if (!p.biasByRow) {
#pragma unroll
        for (int n2 = 0; n2 < NCW; ++n2)
            bcol[n2] = p.bias[col0 + (wn * NCW + n2) * 16 + ln];
    } else {
#pragma unroll
        for (int mt = 0; mt < AM; ++mt)
#pragma unroll
            for (int r = 0; r < 4; ++r)
                brow[mt][r] = p.bias[row0 + wm * (AM * 16) + mt * 16 + qg * 4 + r];
    }

#pragma unroll
    for (int mt = 0; mt < AM; ++mt)
#pragma unroll
        for (int n2 = 0; n2 < NCW; ++n2)
#pragma unroll
            for (int r = 0; r < 4; ++r) {
                int row = row0 + wm * (AM * 16) + mt * 16 + qg * 4 + r;
                int col = col0 + (wn * NCW + n2) * 16 + ln;
                float bb = p.biasByRow ? brow[mt][r] : bcol[n2];
                store_out(&C[(size_t)row * N + col], (acc[mt][n2][r] + bb) * p.scale);
            }
}

// separately-named shells so rocprof shows QKV and out-proj independently
__global__ __launch_bounds__(512, 2) void gemm_qkv_kernel(Gemm3 g)
{
    gemm_body<unsigned short, 16, 16>(g);
}
__global__ __launch_bounds__(512, 2) void gemm_out_kernel(Gemm3 g)
{
    gemm_body<float, 8, 8>(g);
}

// ---------------------------------------------------------------------------
// Flash attention, round-17 = round-4 BR=64 champion (BR=128 regressed
// 49->63 us: doubled per-block serial tile chain, staging was never the
// constraint at 4% HBM) + T13 defer-max: skip the O-rescale when
// __all(pmax - m_run <= 8) — P bounded by 2^8, bf16-safe; first tile
// always rescales (m_run = -3e38). Wave-uniform branch.
// ---------------------------------------------------------------------------
#define BR 64
#define BC 64

__global__ __launch_bounds__(256) void attn_mfma_kernel(
    const unsigned short* __restrict__ Qg, const unsigned short* __restrict__ Kg,
    const unsigned short* __restrict__ VT, unsigned short* __restrict__ O)
{
    __shared__ unsigned short sK[2][8 * 512];   // 16 KB
    __shared__ unsigned short sV[2][8 * 512];   // 16 KB
    __shared__ unsigned short sQ[8 * 512];      // 8 KB

    const int t    = threadIdx.x;
    const int w    = t >> 6;
    const int lane = t & 63;
    const int ln   = lane & 15;
    const int qg   = lane >> 4;

    const int id  = blockIdx.x;
    const int bh  = id & 31;
    const int qt  = (SEQ / BR - 1) - (id >> 5);   // heavy tiles first
    const int b   = bh >> 4;
    const int h   = bh & 15;
    const int qi0 = qt * BR;

    const size_t rowbase = (size_t)b * SEQ;
    const size_t colbase = (size_t)h * DK;

    // ---- stage Q + K/V tile 0 (buf 0) ----
#pragma unroll
    for (int i = 0; i < 2; ++i) {
        const int s = w * 2 + i;
        const int nt = s >> 1, kc = s & 1;
        g2lds16(Qg + (rowbase + qi0 + w * 16 + ln) * DMODEL + colbase + i * 32 + qg * 8,
                &sQ[s * 512]);
        g2lds16(Kg + (rowbase + nt * 16 + ln) * DMODEL + colbase + kc * 32 + qg * 8,
                &sK[0][s * 512]);
        g2lds16(VT + (size_t)(colbase + nt * 16 + ln) * MTOK + rowbase + kc * 32 + qg * 8,
                &sV[0][s * 512]);
    }
    __syncthreads();

    // Q as B-fragment: lane holds Q[q=w*16+ln][d=kc*32+qg*8+j]
    bf16x8 aq[2];
#pragma unroll
    for (int kc = 0; kc < 2; ++kc)
        aq[kc] = *(const bf16x8*)&sQ[(w * 2 + kc) * 512 + lane * 8];

    f32x4 ofrag[4];
#pragma unroll
    for (int nt = 0; nt < 4; ++nt) ofrag[nt] = (f32x4){0.f, 0.f, 0.f, 0.f};
    float osum_p = 0.f;          // per-lane partial denom (own k-slice of q=ln)
    float m_run  = -3.0e38f;     // per-lane running max for q=ln

    // bpermute source lanes for the P-fragment exchange
    const int laneA = ((2 * qg) & 3) * 16 + ln;
    const int laneB = ((2 * qg + 1) & 3) * 16 + ln;
    const bool hiSel = (qg >> 1) & 1;

    const int ntiles = qt + 1;
    for (int jt = 0; jt < ntiles; ++jt) {
        const int cur = jt & 1;

        // ---- prefetch tile jt+1 into the alternate buffer ----
        if (jt + 1 < ntiles) {
            const int j1 = (jt + 1) * BC;
            const int nb = cur ^ 1;
#pragma unroll
            for (int i = 0; i < 2; ++i) {
                const int s = w * 2 + i;
                const int nt = s >> 1, kc = s & 1;
                g2lds16(Kg + (rowbase + j1 + nt * 16 + ln) * DMODEL + colbase + kc * 32 + qg * 8,
                        &sK[nb][s * 512]);
                g2lds16(VT + (size_t)(colbase + nt * 16 + ln) * MTOK + rowbase + j1 + kc * 32 + qg * 8,
                        &sV[nb][s * 512]);
            }
        }

        // ---- S^T = K Q^T (scores pre-scaled by 0.125*log2e) ----
        // sf[nt][r] = S[q=ln][k=nt*16+qg*4+r]
        f32x4 sf[4];
#pragma unroll
        for (int nt = 0; nt < 4; ++nt) {
            f32x4 a2 = (f32x4){0.f, 0.f, 0.f, 0.f};
#pragma unroll
            for (int kc = 0; kc < 2; ++kc) {
                bf16x8 bk = *(const bf16x8*)&sK[cur][(nt * 2 + kc) * 512 + lane * 8];
                a2 = __builtin_amdgcn_mfma_f32_16x16x32_bf16(bk, aq[kc], a2, 0, 0, 0);
            }
            sf[nt] = a2;
        }

        // ---- causal mask (diagonal tile only): k_local > q_local ----
        if (jt == ntiles - 1) {
            const int qloc = w * 16 + ln;
#pragma unroll
            for (int nt = 0; nt < 4; ++nt)
#pragma unroll
                for (int r = 0; r < 4; ++r)
                    if (nt * 16 + qg * 4 + r > qloc) sf[nt][r] = -1.0e30f;
        }

        // ---- online softmax, q-local (T13 defer-max, THR=8) ----
        float pmax = sf[0][0];
#pragma unroll
        for (int nt = 0; nt < 4; ++nt)
#pragma unroll
            for (int r = 0; r < 4; ++r) pmax = fmaxf(pmax, sf[nt][r]);
        pmax = fmaxf(pmax, __shfl_xor(pmax, 16));
        pmax = fmaxf(pmax, __shfl_xor(pmax, 32));

        if (!__all(pmax - m_run <= 8.0f)) {
            // max moved: rescale accumulator + denom, update m_run
            const float mn = fmaxf(m_run, pmax);
            const float al = exp2f(m_run - mn);
            m_run = mn;
            float alr[4];
#pragma unroll
            for (int r = 0; r < 4; ++r) alr[r] = __shfl(al, qg * 4 + r);
#pragma unroll
            for (int nt = 0; nt < 4; ++nt)
#pragma unroll
                for (int r = 0; r < 4; ++r) ofrag[nt][r] *= alr[r];
            osum_p *= al;
        }
        // else: keep stale m_run; P values bounded by exp2(8) = 256 (bf16-safe)

        float pv[4][4];
        float lsum = 0.f;
#pragma unroll
        for (int nt = 0; nt < 4; ++nt)
#pragma unroll
            for (int r = 0; r < 4; ++r) {
                float e = exp2f(sf[nt][r] - m_run);
                pv[nt][r] = e;
                lsum += e;
            }
        osum_p += lsum;

        // ---- pack P to bf16 pairs, exchange into PV A-fragments ----
        unsigned pk0[2], pk1[2], pk2[2], pk3[2];
#pragma unroll
        for (int rr = 0; rr < 2; ++rr) {
            pk0[rr] = cvt_pk_bf16(pv[0][2 * rr], pv[0][2 * rr + 1]);
            pk1[rr] = cvt_pk_bf16(pv[1][2 * rr], pv[1][2 * rr + 1]);
            pk2[rr] = cvt_pk_bf16(pv[2][2 * rr], pv[2][2 * rr + 1]);
            pk3[rr] = cvt_pk_bf16(pv[3][2 * rr], pv[3][2 * rr + 1]);
        }
        union { bf16x8 v; unsigned u[4]; } ap[2];
        {
            unsigned s0, s1;
            s0 = (unsigned)__shfl((int)pk0[0], laneA); s1 = (unsigned)__shfl((int)pk1[0], laneA);
            ap[0].u[0] = hiSel ? s1 : s0;
            s0 = (unsigned)__shfl((int)pk0[1], laneA); s1 = (unsigned)__shfl((int)pk1[1], laneA);
            ap[0].u[1] = hiSel ? s1 : s0;
            s0 = (unsigned)__shfl((int)pk0[0], laneB); s1 = (unsigned)__shfl((int)pk1[0], laneB);
            ap[0].u[2] = hiSel ? s1 : s0;
            s0 = (unsigned)__shfl((int)pk0[1], laneB); s1 = (unsigned)__shfl((int)pk1[1], laneB);
            ap[0].u[3] = hiSel ? s1 : s0;
            s0 = (unsigned)__shfl((int)pk2[0], laneA); s1 = (unsigned)__shfl((int)pk3[0], laneA);
            ap[1].u[0] = hiSel ? s1 : s0;
            s0 = (unsigned)__shfl((int)pk2[1], laneA); s1 = (unsigned)__shfl((int)pk3[1], laneA);
            ap[1].u[1] = hiSel ? s1 : s0;
            s0 = (unsigned)__shfl((int)pk2[0], laneB); s1 = (unsigned)__shfl((int)pk3[0], laneB);
            ap[1].u[2] = hiSel ? s1 : s0;
            s0 = (unsigned)__shfl((int)pk2[1], laneB); s1 = (unsigned)__shfl((int)pk3[1], laneB);
            ap[1].u[3] = hiSel ? s1 : s0;
        }

        // ---- O += P V ----
#pragma unroll
        for (int nt = 0; nt < 4; ++nt) {
#pragma unroll
            for (int kc = 0; kc < 2; ++kc) {
                bf16x8 bv = *(const bf16x8*)&sV[cur][(nt * 2 + kc) * 512 + lane * 8];
                ofrag[nt] = __builtin_amdgcn_mfma_f32_16x16x32_bf16(ap[kc].v, bv, ofrag[nt], 0, 0, 0);
            }
        }

        __syncthreads();    // publish prefetched tile; protect cur for overwrite
    }

    // ---- epilogue: finish denom across k-slices, normalize, write bf16 ----
    float osum = osum_p + __shfl_xor(osum_p, 16);
    osum += __shfl_xor(osum, 32);
    const float invq = 1.0f / osum;     // lane's q = ln
    float inv[4];
#pragma unroll
    for (int r = 0; r < 4; ++r) inv[r] = __shfl(invq, qg * 4 + r);
#pragma unroll
    for (int nt = 0; nt < 4; ++nt)
#pragma unroll
        for (int r = 0; r < 4; ++r) {
            int gq = qi0 + w * 16 + qg * 4 + r;
            O[(rowbase + gq) * DMODEL + colbase + nt * 16 + ln] =
                f2bf(ofrag[nt][r] * inv[r]);
        }
}

// ---------------------------------------------------------------------------
extern "C" void kernel_launch(void* const* d_in, const int* in_sizes, int n_in,
                              void* d_out, int out_size, void* d_ws, size_t ws_size,
                              hipStream_t stream)
{
    const float* q  = (const float*)d_in[0];
    const float* k  = (const float*)d_in[1];
    const float* v  = (const float*)d_in[2];
    // d_in[3] = mask (int32 tril) — causality applied analytically (j<=i).
    const float* wq = (const float*)d_in[4];
    const float* bq = (const float*)d_in[5];
    const float* wk = (const float*)d_in[6];
    const float* bk = (const float*)d_in[7];
    const float* wv = (const float*)d_in[8];
    const float* bv = (const float*)d_in[9];
    const float* wo = (const float*)d_in[10];
    const float* bo = (const float*)d_in[11];
    float* out = (float*)d_out;

    const size_t mat  = (size_t)MTOK * DMODEL;     // 4M elements
    const size_t wmat = (size_t)DMODEL * DMODEL;   // 1M elements
    unsigned short* Abq = (unsigned short*)d_ws;   // bf16 activations
    unsigned short* Abk = Abq + mat;
    unsigned short* Abv = Abk + mat;
    unsigned short* WtQ = Abv + mat;               // bf16 transposed weights
    unsigned short* WtK = WtQ + wmat;
    unsigned short* WtV = WtK + wmat;
    unsigned short* WtO = WtV + wmat;
    unsigned short* Qb  = WtO + wmat;              // bf16 Q proj (pre-scaled)
    unsigned short* Kb  = Qb + mat;                // bf16 K proj
    unsigned short* VT  = Kb + mat;                // bf16 V proj, TRANSPOSED [D][MTOK]
    unsigned short* CTX = VT + mat;                // bf16 attention output

    // merged preprocessing: cvt q/k/v (z 0-2) + 4 weight transposes (z 3-4)
    cvtw_kernel<<<dim3(2048, 1, 5), 256, 0, stream>>>(
        q, k, v, Abq, Abk, Abv, wq, wk, wv, wo, WtQ, WtK, WtV, WtO, (int)mat);

    // fused projections: z0=Q (pre-scaled by 0.125*log2e), z1=K, z2=V transposed.
    // 256x256 tiles: z0/z1: 16x4 = 64 blocks (ctShift=2); z2 (swapped, C=VT
    // [1024 x 4096]): 4x16 = 64 blocks (ctShift=4). Total 192 (%8==0).
    const float qscale = 0.125f * 1.44269504088896f;
    Gemm3 g;
    g.p[0] = (GemmP){Abq, WtQ, bq, (void*)Qb, DMODEL, DMODEL, 2, 0, qscale};
    g.p[1] = (GemmP){Abk, WtK, bk, (void*)Kb, DMODEL, DMODEL, 2, 0, 1.0f};
    g.p[2] = (GemmP){WtV, Abv, bv, (void*)VT, MTOK,   DMODEL, 4, 1, 1.0f};  // swapped operands
    gemm_qkv_kernel<<<dim3(64, 1, 3), 512, 0, stream>>>(g);

    // attention: 1024 blocks of 256 threads (BR=64, heavy-first)
    attn_mfma_kernel<<<BATCH * NHEAD * (SEQ / BR), 256, 0, stream>>>(Qb, Kb, VT, CTX);

    // output projection: plain 128x128 tiles -> 32x8 = 256 blocks
    Gemm3 go;
    go.p[0] = (GemmP){CTX, WtO, bo, (void*)out, DMODEL, DMODEL, 3, 0, 1.0f};
    go.p[1] = go.p[0];
    go.p[2] = go.p[0];
    gemm_out_kernel<<<dim3(256, 1, 1), 512, 0, stream>>>(go);
}